// Round 1
// baseline (1890.733 us; speedup 1.0000x reference)
//
#include <hip/hip_runtime.h>
#include <cstdio>
#include <cstdint>

// Problem constants
#define B_    16
#define N_    577
#define C_    768
#define H_    12
#define D_    64
#define KKEEP 288            // max(1, int(576*0.5))
#define SCALE 0.125f         // 64^-0.5

// ---------------------------------------------------------------------------
// dot of two 64-float rows (q row held in registers as 16 float4)
// ---------------------------------------------------------------------------
__device__ __forceinline__ float dot64(const float4* qr, const float* kp) {
    const float4* k4 = (const float4*)kp;
    float s = 0.f;
#pragma unroll
    for (int i = 0; i < 16; i++) {
        float4 a = qr[i], bv = k4[i];
        s += a.x * bv.x; s += a.y * bv.y; s += a.z * bv.z; s += a.w * bv.w;
    }
    return s;
}

// ---------------------------------------------------------------------------
// GEMM 1: qkv = x @ Wqkv^T, scattered to q/k/v in [B,H,N,D] layout.
// A: [M=9232, K=768] row-major. W: [2304, 768] row-major.
// 64x64 tile, BK=16, 256 threads, 4x4 micro-tile.
// ---------------------------------------------------------------------------
__global__ __launch_bounds__(256) void gemm_qkv(const float* __restrict__ A,
                                                const float* __restrict__ W,
                                                float* __restrict__ qout,
                                                float* __restrict__ kout,
                                                float* __restrict__ vout) {
    const int M = B_ * N_, K = C_;
    __shared__ float As[16][68];
    __shared__ float Ws[16][68];
    int tid = threadIdx.x;
    int tm = tid >> 4, tn = tid & 15;
    int m0 = blockIdx.y * 64, n0 = blockIdx.x * 64;
    int lrow = tid >> 2, lk = (tid & 3) * 4;
    bool aval = (m0 + lrow) < M;
    const float* Arow = A + (size_t)(m0 + lrow) * K;
    const float* Wrow = W + (size_t)(n0 + lrow) * K;
    float acc[4][4] = {};
    for (int k0 = 0; k0 < K; k0 += 16) {
        float4 av = aval ? *(const float4*)(Arow + k0 + lk) : make_float4(0, 0, 0, 0);
        float4 wv = *(const float4*)(Wrow + k0 + lk);
        As[lk + 0][lrow] = av.x; As[lk + 1][lrow] = av.y;
        As[lk + 2][lrow] = av.z; As[lk + 3][lrow] = av.w;
        Ws[lk + 0][lrow] = wv.x; Ws[lk + 1][lrow] = wv.y;
        Ws[lk + 2][lrow] = wv.z; Ws[lk + 3][lrow] = wv.w;
        __syncthreads();
#pragma unroll
        for (int kk = 0; kk < 16; kk++) {
            float a0[4], b0[4];
            *(float4*)a0 = *(const float4*)&As[kk][tm * 4];
            *(float4*)b0 = *(const float4*)&Ws[kk][tn * 4];
#pragma unroll
            for (int i = 0; i < 4; i++)
#pragma unroll
                for (int j = 0; j < 4; j++) acc[i][j] += a0[i] * b0[j];
        }
        __syncthreads();
    }
    // whole block's column range [n0, n0+64) lies in one (s, h) slice
    int s = n0 / C_;
    int h = (n0 % C_) / D_;
    float* dst = (s == 0) ? qout : (s == 1) ? kout : vout;
#pragma unroll
    for (int i = 0; i < 4; i++) {
        int gm = m0 + tm * 4 + i;
        if (gm < M) {
            int b = gm / N_, n = gm % N_;
            float4 o = make_float4(acc[i][0], acc[i][1], acc[i][2], acc[i][3]);
            *(float4*)&dst[(((size_t)(b * H_ + h) * N_ + n) * D_) + tn * 4] = o;
        }
    }
}

// ---------------------------------------------------------------------------
// GEMM 2: out = context @ Wproj^T + bproj
// ---------------------------------------------------------------------------
__global__ __launch_bounds__(256) void gemm_proj(const float* __restrict__ A,
                                                 const float* __restrict__ W,
                                                 const float* __restrict__ bias,
                                                 float* __restrict__ Cout) {
    const int M = B_ * N_, K = C_, Nn = C_;
    __shared__ float As[16][68];
    __shared__ float Ws[16][68];
    int tid = threadIdx.x;
    int tm = tid >> 4, tn = tid & 15;
    int m0 = blockIdx.y * 64, n0 = blockIdx.x * 64;
    int lrow = tid >> 2, lk = (tid & 3) * 4;
    bool aval = (m0 + lrow) < M;
    const float* Arow = A + (size_t)(m0 + lrow) * K;
    const float* Wrow = W + (size_t)(n0 + lrow) * K;
    float acc[4][4] = {};
    for (int k0 = 0; k0 < K; k0 += 16) {
        float4 av = aval ? *(const float4*)(Arow + k0 + lk) : make_float4(0, 0, 0, 0);
        float4 wv = *(const float4*)(Wrow + k0 + lk);
        As[lk + 0][lrow] = av.x; As[lk + 1][lrow] = av.y;
        As[lk + 2][lrow] = av.z; As[lk + 3][lrow] = av.w;
        Ws[lk + 0][lrow] = wv.x; Ws[lk + 1][lrow] = wv.y;
        Ws[lk + 2][lrow] = wv.z; Ws[lk + 3][lrow] = wv.w;
        __syncthreads();
#pragma unroll
        for (int kk = 0; kk < 16; kk++) {
            float a0[4], b0[4];
            *(float4*)a0 = *(const float4*)&As[kk][tm * 4];
            *(float4*)b0 = *(const float4*)&Ws[kk][tn * 4];
#pragma unroll
            for (int i = 0; i < 4; i++)
#pragma unroll
                for (int j = 0; j < 4; j++) acc[i][j] += a0[i] * b0[j];
        }
        __syncthreads();
    }
#pragma unroll
    for (int i = 0; i < 4; i++) {
        int gm = m0 + tm * 4 + i;
        if (gm < M) {
            int nc = n0 + tn * 4;
            float4 bb = *(const float4*)&bias[nc];
            float4 o = make_float4(acc[i][0] + bb.x, acc[i][1] + bb.y,
                                   acc[i][2] + bb.z, acc[i][3] + bb.w);
            *(float4*)&Cout[(size_t)gm * Nn + nc] = o;
        }
    }
}

// ---------------------------------------------------------------------------
// Pass A: per (b,h): softmax row stats + deterministic per-chunk column sums.
// grid (3 chunks, B*H), 256 threads; thread <-> query.
// ---------------------------------------------------------------------------
__global__ __launch_bounds__(256) void attn_colsum(const float* __restrict__ q,
                                                   const float* __restrict__ k,
                                                   float* __restrict__ rowmax,
                                                   float* __restrict__ rowsum,
                                                   float* __restrict__ colsum_part) {
    int bh = blockIdx.y;
    int chunk = blockIdx.x;
    int qi = chunk * 256 + threadIdx.x;
    bool valid = qi < N_;
    int qic = valid ? qi : (N_ - 1);
    const float* qp = q + ((size_t)bh * N_ + qic) * D_;
    float4 qr[16];
#pragma unroll
    for (int i = 0; i < 16; i++) qr[i] = ((const float4*)qp)[i];
    const float* kb = k + (size_t)bh * N_ * D_;

    // loop 1: online max / sum-of-exp
    float mrow = -INFINITY, lrow = 0.f;
    for (int j = 0; j < N_; j++) {
        float s = dot64(qr, kb + (size_t)j * D_) * SCALE;
        if (s > mrow) {
            lrow = lrow * expf(mrow - s) + 1.f;
            mrow = s;
        } else {
            lrow += expf(s - mrow);
        }
    }
    if (valid) {
        rowmax[(size_t)bh * N_ + qi] = mrow;
        rowsum[(size_t)bh * N_ + qi] = lrow;
    }

    // loop 2: accumulate column sums of probs (wave-reduced, no atomics)
    __shared__ float cs[4][N_];
    for (int t = threadIdx.x; t < 4 * N_; t += 256) (&cs[0][0])[t] = 0.f;
    __syncthreads();
    int wave = threadIdx.x >> 6, lane = threadIdx.x & 63;
    float invl = 1.f / lrow;
    for (int j = 0; j < N_; j++) {
        float s = dot64(qr, kb + (size_t)j * D_) * SCALE;
        float p = valid ? expf(s - mrow) * invl : 0.f;
#pragma unroll
        for (int off = 32; off; off >>= 1) p += __shfl_down(p, off);
        if (lane == 0) cs[wave][j] += p;
    }
    __syncthreads();
    float* cp = colsum_part + (size_t)chunk * (B_ * H_ * N_) + (size_t)bh * N_;
    for (int j = threadIdx.x; j < N_; j += 256)
        cp[j] = cs[0][j] + cs[1][j] + cs[2][j] + cs[3][j];
}

// ---------------------------------------------------------------------------
// Top-k per batch: UCB scores + full bitonic sort (desc, ties -> lower index)
// ---------------------------------------------------------------------------
__global__ __launch_bounds__(512) void topk_kernel(const float* __restrict__ colsum_part,
                                                   const float* __restrict__ ucb_count,
                                                   const int* __restrict__ counter,
                                                   float* __restrict__ kept_out,
                                                   float* __restrict__ kvmask) {
    __shared__ float sv[1024];
    __shared__ int si[1024];
    int b = blockIdx.x, tid = threadIdx.x;
    float lc = logf((float)counter[0] + 1.0f);
    const int BHN = B_ * H_ * N_;
    for (int t = tid; t < 1024; t += 512) {
        if (t < N_ - 1) {
            int tok = t + 1;
            float accv = 0.f;
#pragma unroll
            for (int h = 0; h < H_; h++) {
                size_t idx = (size_t)(b * H_ + h) * N_ + tok;
                float csv = colsum_part[idx] + colsum_part[BHN + idx] +
                            colsum_part[2 * (size_t)BHN + idx];
                float patch = csv * (1.0f / (float)N_);
                float cnt = ucb_count[h * N_ + tok];
                float expl = sqrtf(lc / (cnt + 1e-6f));
                accv += patch + expl;
            }
            sv[t] = accv * (1.0f / (float)H_);
            si[t] = t;  // relative index (token-1)
        } else {
            sv[t] = -INFINITY;
            si[t] = 1 << 20;
        }
    }
    __syncthreads();
    for (int kk = 2; kk <= 1024; kk <<= 1) {
        for (int jj = kk >> 1; jj > 0; jj >>= 1) {
            for (int t = tid; t < 1024; t += 512) {
                int ixj = t ^ jj;
                if (ixj > t) {
                    float v1 = sv[t], v2 = sv[ixj];
                    int i1 = si[t], i2 = si[ixj];
                    // true if element at ixj must precede element at t in
                    // descending order (value desc, index asc on ties)
                    bool before21 = (v2 > v1) || (v2 == v1 && i2 < i1);
                    bool dirDesc = ((t & kk) == 0);
                    if (before21 == dirDesc) {
                        sv[t] = v2; sv[ixj] = v1;
                        si[t] = i2; si[ixj] = i1;
                    }
                }
            }
            __syncthreads();
        }
    }
    for (int r = tid; r < KKEEP; r += 512) {
        int tok = si[r] + 1;
        kept_out[b * KKEEP + r] = (float)tok;   // output buffer is float32
        kvmask[b * N_ + tok] = 1.0f;
    }
    if (tid == 0) kvmask[b * N_] = 1.0f;  // CLS always kept
}

// ---------------------------------------------------------------------------
// score_delta[h,n] = (1/B) * count_b(token n kept)   (n=0 -> 0)
// ---------------------------------------------------------------------------
__global__ void score_delta_kernel(const float* __restrict__ kvmask,
                                   float* __restrict__ sd) {
    int idx = blockIdx.x * 256 + threadIdx.x;
    if (idx >= H_ * N_) return;
    int n = idx % N_;
    float d = 0.f;
    if (n != 0) {
#pragma unroll
        for (int b = 0; b < B_; b++) d += kvmask[b * N_ + n];
    }
    sd[idx] = d * (1.0f / (float)B_);
}

// ---------------------------------------------------------------------------
// Pass B: masked context.  context[b,n, h*64+d] layout for the proj GEMM.
// ---------------------------------------------------------------------------
__global__ __launch_bounds__(256) void attn_context(const float* __restrict__ q,
                                                    const float* __restrict__ k,
                                                    const float* __restrict__ v,
                                                    const float* __restrict__ rowmax,
                                                    const float* __restrict__ rowsum,
                                                    const float* __restrict__ kvmask,
                                                    float* __restrict__ context) {
    int bh = blockIdx.y;
    int b = bh / H_, h = bh % H_;
    int qi = blockIdx.x * 256 + threadIdx.x;
    bool valid = qi < N_;
    int qic = valid ? qi : (N_ - 1);
    const float* qp = q + ((size_t)bh * N_ + qic) * D_;
    float4 qr[16];
#pragma unroll
    for (int i = 0; i < 16; i++) qr[i] = ((const float4*)qp)[i];
    float mrow = rowmax[(size_t)bh * N_ + qic];
    float invl = 1.f / rowsum[(size_t)bh * N_ + qic];
    float kvq = kvmask[b * N_ + qic];
    bool keepall = kvq > 0.5f;  // kept query -> mask row is all ones
    const float* kb = k + (size_t)bh * N_ * D_;
    const float* vb = v + (size_t)bh * N_ * D_;
    float4 acc[16] = {};
    float psum = 0.f;
    for (int j = 0; j < N_; j++) {
        float kvj = kvmask[b * N_ + j];
        float s = dot64(qr, kb + (size_t)j * D_) * SCALE;
        float p = expf(s - mrow) * invl;
        float u = (keepall || kvj > 0.5f) ? 1.f : 0.f;
        p *= u;
        psum += p;
        const float4* vp = (const float4*)(vb + (size_t)j * D_);
#pragma unroll
        for (int i = 0; i < 16; i++) {
            float4 vv = vp[i];
            acc[i].x += p * vv.x; acc[i].y += p * vv.y;
            acc[i].z += p * vv.z; acc[i].w += p * vv.w;
        }
    }
    if (valid) {
        float rn = 1.f / (psum + 1e-8f);
        float* cp = context + (size_t)(b * N_ + qi) * C_ + h * D_;
#pragma unroll
        for (int i = 0; i < 16; i++) {
            float4 o = make_float4(acc[i].x * rn, acc[i].y * rn,
                                   acc[i].z * rn, acc[i].w * rn);
            ((float4*)cp)[i] = o;
        }
    }
}

// ---------------------------------------------------------------------------
extern "C" void kernel_launch(void* const* d_in, const int* in_sizes, int n_in,
                              void* d_out, int out_size, void* d_ws, size_t ws_size,
                              hipStream_t stream) {
    const float* x     = (const float*)d_in[0];
    const float* ucb   = (const float*)d_in[1];
    const float* Wqkv  = (const float*)d_in[2];
    const float* Wproj = (const float*)d_in[3];
    const float* bproj = (const float*)d_in[4];
    const int*   counter = (const int*)d_in[5];

    const size_t SZ  = (size_t)B_ * H_ * N_ * D_;  // 7,090,176
    const size_t BHN = (size_t)B_ * H_ * N_;       // 110,784
    float* q        = (float*)d_ws;
    float* k        = q + SZ;
    float* v        = k + SZ;
    float* context  = v + SZ;
    float* rowmax   = context + SZ;
    float* rowsum   = rowmax + BHN;
    float* colsum_p = rowsum + BHN;                 // 3 * BHN
    float* kvmask   = colsum_p + 3 * BHN;
    size_t need = (size_t)(kvmask + (size_t)B_ * N_ - (float*)d_ws) * sizeof(float);
    if (ws_size < need) {
        fprintf(stderr, "kernel_launch: ws too small, need %zu have %zu\n",
                need, ws_size);
        return;
    }

    float* out  = (float*)d_out;
    float* sd   = out + (size_t)B_ * N_ * C_;
    float* kept = sd + (size_t)H_ * N_;

    hipMemsetAsync(kvmask, 0, (size_t)B_ * N_ * sizeof(float), stream);

    gemm_qkv<<<dim3(36, 145), 256, 0, stream>>>(x, Wqkv, q, k, v);
    attn_colsum<<<dim3(3, B_ * H_), 256, 0, stream>>>(q, k, rowmax, rowsum, colsum_p);
    topk_kernel<<<B_, 512, 0, stream>>>(colsum_p, ucb, counter, kept, kvmask);
    score_delta_kernel<<<(H_ * N_ + 255) / 256, 256, 0, stream>>>(kvmask, sd);
    attn_context<<<dim3(3, B_ * H_), 256, 0, stream>>>(q, k, v, rowmax, rowsum,
                                                       kvmask, context);
    gemm_proj<<<dim3(12, 145), 256, 0, stream>>>(context, Wproj, bproj, out);
}

// Round 2
// 1263.722 us; speedup vs baseline: 1.4962x; 1.4962x over previous
//
#include <hip/hip_runtime.h>
#include <cstdio>
#include <cstdint>

// Problem constants
#define B_    16
#define N_    577
#define C_    768
#define H_    12
#define D_    64
#define KKEEP 288            // max(1, int(576*0.5))
#define SCALE 0.125f         // 64^-0.5

// ---------------------------------------------------------------------------
// Stage a 64-row x 64-col (row=token, col=d) tile from global [N][64] into
// LDS TRANSPOSED: dst[d][row]. Rows >= N_ staged as zeros. Optional scale.
// ---------------------------------------------------------------------------
__device__ __forceinline__ void stage_tile_T(const float* __restrict__ base, int row0,
                                             float (*dst)[68], int tid, float scale) {
    int lrow = tid >> 2, lk4 = (tid & 3) * 16;
    int rn = row0 + lrow;
    bool valid = rn < N_;
    const float* src = base + (size_t)rn * D_ + lk4;
#pragma unroll
    for (int g = 0; g < 4; g++) {
        float4 val = valid ? *(const float4*)(src + g * 4) : make_float4(0.f, 0.f, 0.f, 0.f);
        dst[lk4 + g * 4 + 0][lrow] = val.x * scale;
        dst[lk4 + g * 4 + 1][lrow] = val.y * scale;
        dst[lk4 + g * 4 + 2][lrow] = val.z * scale;
        dst[lk4 + g * 4 + 3][lrow] = val.w * scale;
    }
}

// 4x4 micro-GEMM over the 64-deep d dimension: sacc[qi][jj] += Q.K
__device__ __forceinline__ void smicro(const float (*Qs)[68], const float (*Ks)[68],
                                       int tm, int tn, float sacc[4][4]) {
#pragma unroll 16
    for (int kk = 0; kk < 64; kk++) {
        float a0[4], b0[4];
        *(float4*)a0 = *(const float4*)&Qs[kk][tm * 4];
        *(float4*)b0 = *(const float4*)&Ks[kk][tn * 4];
#pragma unroll
        for (int qi = 0; qi < 4; qi++)
#pragma unroll
            for (int jj = 0; jj < 4; jj++)
                sacc[qi][jj] += a0[qi] * b0[jj];
    }
}

// ---------------------------------------------------------------------------
// GEMM 1: qkv = x @ Wqkv^T, scattered to q/k/v in [B,H,N,D] layout.
// ---------------------------------------------------------------------------
__global__ __launch_bounds__(256) void gemm_qkv(const float* __restrict__ A,
                                                const float* __restrict__ W,
                                                float* __restrict__ qout,
                                                float* __restrict__ kout,
                                                float* __restrict__ vout) {
    const int M = B_ * N_, K = C_;
    __shared__ float As[16][68];
    __shared__ float Ws[16][68];
    int tid = threadIdx.x;
    int tm = tid >> 4, tn = tid & 15;
    int m0 = blockIdx.y * 64, n0 = blockIdx.x * 64;
    int lrow = tid >> 2, lk = (tid & 3) * 4;
    bool aval = (m0 + lrow) < M;
    const float* Arow = A + (size_t)(m0 + lrow) * K;
    const float* Wrow = W + (size_t)(n0 + lrow) * K;
    float acc[4][4] = {};
    for (int k0 = 0; k0 < K; k0 += 16) {
        float4 av = aval ? *(const float4*)(Arow + k0 + lk) : make_float4(0, 0, 0, 0);
        float4 wv = *(const float4*)(Wrow + k0 + lk);
        As[lk + 0][lrow] = av.x; As[lk + 1][lrow] = av.y;
        As[lk + 2][lrow] = av.z; As[lk + 3][lrow] = av.w;
        Ws[lk + 0][lrow] = wv.x; Ws[lk + 1][lrow] = wv.y;
        Ws[lk + 2][lrow] = wv.z; Ws[lk + 3][lrow] = wv.w;
        __syncthreads();
#pragma unroll
        for (int kk = 0; kk < 16; kk++) {
            float a0[4], b0[4];
            *(float4*)a0 = *(const float4*)&As[kk][tm * 4];
            *(float4*)b0 = *(const float4*)&Ws[kk][tn * 4];
#pragma unroll
            for (int i = 0; i < 4; i++)
#pragma unroll
                for (int j = 0; j < 4; j++) acc[i][j] += a0[i] * b0[j];
        }
        __syncthreads();
    }
    int s = n0 / C_;
    int h = (n0 % C_) / D_;
    float* dst = (s == 0) ? qout : (s == 1) ? kout : vout;
#pragma unroll
    for (int i = 0; i < 4; i++) {
        int gm = m0 + tm * 4 + i;
        if (gm < M) {
            int b = gm / N_, n = gm % N_;
            float4 o = make_float4(acc[i][0], acc[i][1], acc[i][2], acc[i][3]);
            *(float4*)&dst[(((size_t)(b * H_ + h) * N_ + n) * D_) + tn * 4] = o;
        }
    }
}

// ---------------------------------------------------------------------------
// GEMM 2: out = context @ Wproj^T + bproj
// ---------------------------------------------------------------------------
__global__ __launch_bounds__(256) void gemm_proj(const float* __restrict__ A,
                                                 const float* __restrict__ W,
                                                 const float* __restrict__ bias,
                                                 float* __restrict__ Cout) {
    const int M = B_ * N_, K = C_, Nn = C_;
    __shared__ float As[16][68];
    __shared__ float Ws[16][68];
    int tid = threadIdx.x;
    int tm = tid >> 4, tn = tid & 15;
    int m0 = blockIdx.y * 64, n0 = blockIdx.x * 64;
    int lrow = tid >> 2, lk = (tid & 3) * 4;
    bool aval = (m0 + lrow) < M;
    const float* Arow = A + (size_t)(m0 + lrow) * K;
    const float* Wrow = W + (size_t)(n0 + lrow) * K;
    float acc[4][4] = {};
    for (int k0 = 0; k0 < K; k0 += 16) {
        float4 av = aval ? *(const float4*)(Arow + k0 + lk) : make_float4(0, 0, 0, 0);
        float4 wv = *(const float4*)(Wrow + k0 + lk);
        As[lk + 0][lrow] = av.x; As[lk + 1][lrow] = av.y;
        As[lk + 2][lrow] = av.z; As[lk + 3][lrow] = av.w;
        Ws[lk + 0][lrow] = wv.x; Ws[lk + 1][lrow] = wv.y;
        Ws[lk + 2][lrow] = wv.z; Ws[lk + 3][lrow] = wv.w;
        __syncthreads();
#pragma unroll
        for (int kk = 0; kk < 16; kk++) {
            float a0[4], b0[4];
            *(float4*)a0 = *(const float4*)&As[kk][tm * 4];
            *(float4*)b0 = *(const float4*)&Ws[kk][tn * 4];
#pragma unroll
            for (int i = 0; i < 4; i++)
#pragma unroll
                for (int j = 0; j < 4; j++) acc[i][j] += a0[i] * b0[j];
        }
        __syncthreads();
    }
#pragma unroll
    for (int i = 0; i < 4; i++) {
        int gm = m0 + tm * 4 + i;
        if (gm < M) {
            int nc = n0 + tn * 4;
            float4 bb = *(const float4*)&bias[nc];
            float4 o = make_float4(acc[i][0] + bb.x, acc[i][1] + bb.y,
                                   acc[i][2] + bb.z, acc[i][3] + bb.w);
            *(float4*)&Cout[(size_t)gm * Nn + nc] = o;
        }
    }
}

// ---------------------------------------------------------------------------
// Pass R: w[bh][q] = 1 / sum_j exp(scale * q.k)    (no max needed, |s| small)
// grid (10 q-tiles, 192 bh), 256 threads, 4x4 micro-tiles.
// ---------------------------------------------------------------------------
__global__ __launch_bounds__(256) void attn_rowsum(const float* __restrict__ q,
                                                   const float* __restrict__ k,
                                                   float* __restrict__ w) {
    int bh = blockIdx.y;
    int q0 = blockIdx.x * 64;
    __shared__ float Qs[64][68];
    __shared__ float Ks[64][68];
    __shared__ float red[16][68];
    int tid = threadIdx.x, tm = tid >> 4, tn = tid & 15;
    const float* qb = q + (size_t)bh * N_ * D_;
    const float* kb = k + (size_t)bh * N_ * D_;
    stage_tile_T(qb, q0, Qs, tid, SCALE);
    float rs[4] = {0.f, 0.f, 0.f, 0.f};
    for (int j0 = 0; j0 < N_; j0 += 64) {
        __syncthreads();
        stage_tile_T(kb, j0, Ks, tid, 1.0f);
        __syncthreads();
        float sacc[4][4] = {};
        smicro(Qs, Ks, tm, tn, sacc);
#pragma unroll
        for (int jj = 0; jj < 4; jj++) {
            int j = j0 + tn * 4 + jj;
            if (j < N_) {
#pragma unroll
                for (int qi = 0; qi < 4; qi++) rs[qi] += __expf(sacc[qi][jj]);
            }
        }
    }
    __syncthreads();
#pragma unroll
    for (int qi = 0; qi < 4; qi++) red[tn][tm * 4 + qi] = rs[qi];
    __syncthreads();
    if (tid < 64) {
        float s = 0.f;
#pragma unroll
        for (int t = 0; t < 16; t++) s += red[t][tid];
        int qn = q0 + tid;
        if (qn < N_) w[(size_t)bh * N_ + qn] = 1.0f / s;
    }
}

// ---------------------------------------------------------------------------
// Pass CS: colsum[bh][j] = sum_q exp(s)*w[q]  (deterministic fixed-order)
// grid (10 j-tiles, 192 bh).
// ---------------------------------------------------------------------------
__global__ __launch_bounds__(256) void attn_colsum2(const float* __restrict__ q,
                                                    const float* __restrict__ k,
                                                    const float* __restrict__ w,
                                                    float* __restrict__ colsum) {
    int bh = blockIdx.y;
    int j0 = blockIdx.x * 64;
    __shared__ float Qs[64][68];
    __shared__ float Ks[64][68];
    __shared__ float red[16][68];
    int tid = threadIdx.x, tm = tid >> 4, tn = tid & 15;
    const float* qb = q + (size_t)bh * N_ * D_;
    const float* kb = k + (size_t)bh * N_ * D_;
    stage_tile_T(kb, j0, Ks, tid, SCALE);   // fold scale into K here
    float cs[4] = {0.f, 0.f, 0.f, 0.f};
    for (int qt = 0; qt < N_; qt += 64) {
        __syncthreads();
        stage_tile_T(qb, qt, Qs, tid, 1.0f);
        __syncthreads();
        float sacc[4][4] = {};
        smicro(Qs, Ks, tm, tn, sacc);
        float wv[4];
#pragma unroll
        for (int qi = 0; qi < 4; qi++) {
            int qn = qt + tm * 4 + qi;
            wv[qi] = (qn < N_) ? w[(size_t)bh * N_ + qn] : 0.f;
        }
#pragma unroll
        for (int jj = 0; jj < 4; jj++) {
            int j = j0 + tn * 4 + jj;
            if (j < N_) {
#pragma unroll
                for (int qi = 0; qi < 4; qi++)
                    cs[jj] += __expf(sacc[qi][jj]) * wv[qi];
            }
        }
    }
    __syncthreads();
#pragma unroll
    for (int jj = 0; jj < 4; jj++) red[tm][tn * 4 + jj] = cs[jj];
    __syncthreads();
    if (tid < 64) {
        float s = 0.f;
#pragma unroll
        for (int t = 0; t < 16; t++) s += red[t][tid];
        int j = j0 + tid;
        if (j < N_) colsum[(size_t)bh * N_ + j] = s;
    }
}

// ---------------------------------------------------------------------------
// Top-k per batch: UCB scores + full bitonic sort (desc, ties -> lower index)
// ---------------------------------------------------------------------------
__global__ __launch_bounds__(512) void topk_kernel(const float* __restrict__ colsum,
                                                   const float* __restrict__ ucb_count,
                                                   const int* __restrict__ counter,
                                                   float* __restrict__ kept_out,
                                                   float* __restrict__ kvmask) {
    __shared__ float sv[1024];
    __shared__ int si[1024];
    int b = blockIdx.x, tid = threadIdx.x;
    float lc = logf((float)counter[0] + 1.0f);
    for (int t = tid; t < 1024; t += 512) {
        if (t < N_ - 1) {
            int tok = t + 1;
            float accv = 0.f;
#pragma unroll
            for (int h = 0; h < H_; h++) {
                float csv = colsum[(size_t)(b * H_ + h) * N_ + tok];
                float patch = csv * (1.0f / (float)N_);
                float cnt = ucb_count[h * N_ + tok];
                float expl = sqrtf(lc / (cnt + 1e-6f));
                accv += patch + expl;
            }
            sv[t] = accv * (1.0f / (float)H_);
            si[t] = t;
        } else {
            sv[t] = -INFINITY;
            si[t] = 1 << 20;
        }
    }
    __syncthreads();
    for (int kk = 2; kk <= 1024; kk <<= 1) {
        for (int jj = kk >> 1; jj > 0; jj >>= 1) {
            for (int t = tid; t < 1024; t += 512) {
                int ixj = t ^ jj;
                if (ixj > t) {
                    float v1 = sv[t], v2 = sv[ixj];
                    int i1 = si[t], i2 = si[ixj];
                    bool before21 = (v2 > v1) || (v2 == v1 && i2 < i1);
                    bool dirDesc = ((t & kk) == 0);
                    if (before21 == dirDesc) {
                        sv[t] = v2; sv[ixj] = v1;
                        si[t] = i2; si[ixj] = i1;
                    }
                }
            }
            __syncthreads();
        }
    }
    for (int r = tid; r < KKEEP; r += 512) {
        int tok = si[r] + 1;
        kept_out[b * KKEEP + r] = (float)tok;
        kvmask[b * N_ + tok] = 1.0f;
    }
    if (tid == 0) kvmask[b * N_] = 1.0f;  // CLS always kept
}

// ---------------------------------------------------------------------------
// score_delta[h,n] = (1/B) * count_b(token n kept)   (n=0 -> 0)
// ---------------------------------------------------------------------------
__global__ void score_delta_kernel(const float* __restrict__ kvmask,
                                   float* __restrict__ sd) {
    int idx = blockIdx.x * 256 + threadIdx.x;
    if (idx >= H_ * N_) return;
    int n = idx % N_;
    float d = 0.f;
    if (n != 0) {
#pragma unroll
        for (int b = 0; b < B_; b++) d += kvmask[b * N_ + n];
    }
    sd[idx] = d * (1.0f / (float)B_);
}

// ---------------------------------------------------------------------------
// Pass CTX: masked, renormalized context. One block per (q-tile, bh).
// Per j-tile: S micro-GEMM -> p = exp*w*mask staged to LDS -> PV micro-GEMM.
// context layout [b,n, h*64+d] for the proj GEMM.
// ---------------------------------------------------------------------------
__global__ __launch_bounds__(256) void attn_ctx(const float* __restrict__ q,
                                                const float* __restrict__ k,
                                                const float* __restrict__ v,
                                                const float* __restrict__ w,
                                                const float* __restrict__ kvmask,
                                                float* __restrict__ context) {
    int bh = blockIdx.y, b = bh / H_, h = bh % H_;
    int q0 = blockIdx.x * 64;
    __shared__ float Qs[64][68];
    __shared__ float KVs[64][68];   // K (transposed) in phase 1, V (natural) in phase 2
    __shared__ float Ps[64][68];    // P tile [j][q]; reused as reduction buffer at end
    int tid = threadIdx.x, tm = tid >> 4, tn = tid & 15;
    const float* qb = q + (size_t)bh * N_ * D_;
    const float* kb = k + (size_t)bh * N_ * D_;
    const float* vb = v + (size_t)bh * N_ * D_;
    stage_tile_T(qb, q0, Qs, tid, SCALE);
    float wv[4], mq[4];
#pragma unroll
    for (int qi = 0; qi < 4; qi++) {
        int qn = q0 + tm * 4 + qi;
        wv[qi] = (qn < N_) ? w[(size_t)bh * N_ + qn] : 0.f;
        mq[qi] = (qn < N_) ? kvmask[b * N_ + qn] : 0.f;
    }
    float acc[4][4] = {};
    float ps[4] = {0.f, 0.f, 0.f, 0.f};
    int lrow = tid >> 2, lk4 = (tid & 3) * 16;
    for (int j0 = 0; j0 < N_; j0 += 64) {
        __syncthreads();                       // prev-iter Ps/V reads done
        stage_tile_T(kb, j0, KVs, tid, 1.0f);
        __syncthreads();
        float sacc[4][4] = {};
        smicro(Qs, KVs, tm, tn, sacc);
        float4 pr[4];
#pragma unroll
        for (int jj = 0; jj < 4; jj++) {
            int j = j0 + tn * 4 + jj;
            float mj = (j < N_) ? kvmask[b * N_ + j] : 0.f;
            float pv[4];
#pragma unroll
            for (int qi = 0; qi < 4; qi++) {
                float p = (j < N_) ? __expf(sacc[qi][jj]) * wv[qi] : 0.f;
                if (!(mq[qi] > 0.5f || mj > 0.5f)) p = 0.f;
                pv[qi] = p;
                ps[qi] += p;
            }
            pr[jj] = make_float4(pv[0], pv[1], pv[2], pv[3]);
        }
        __syncthreads();                       // done reading K from KVs
        // stage V tile (natural [j][d] layout) into KVs
        {
            int jn = j0 + lrow;
            bool vvok = jn < N_;
            const float* src = vb + (size_t)jn * D_ + lk4;
#pragma unroll
            for (int g = 0; g < 4; g++) {
                float4 val = vvok ? *(const float4*)(src + g * 4)
                                  : make_float4(0.f, 0.f, 0.f, 0.f);
                *(float4*)&KVs[lrow][lk4 + g * 4] = val;
            }
        }
        // write P tile [j][q]
#pragma unroll
        for (int jj = 0; jj < 4; jj++)
            *(float4*)&Ps[tn * 4 + jj][tm * 4] = pr[jj];
        __syncthreads();
        // PV accumulate: acc[qi][di] += P[q][j] * V[j][d]
#pragma unroll 16
        for (int jj2 = 0; jj2 < 64; jj2++) {
            float a0[4], b0[4];
            *(float4*)a0 = *(const float4*)&Ps[jj2][tm * 4];
            *(float4*)b0 = *(const float4*)&KVs[jj2][tn * 4];
#pragma unroll
            for (int qi = 0; qi < 4; qi++)
#pragma unroll
                for (int di = 0; di < 4; di++)
                    acc[qi][di] += a0[qi] * b0[di];
        }
    }
    // reduce psum across tn (reuse Ps rows 0..16 as scratch)
    __syncthreads();
    float (*red)[68] = (float(*)[68])Ps;
#pragma unroll
    for (int qi = 0; qi < 4; qi++) red[tn][tm * 4 + qi] = ps[qi];
    __syncthreads();
    float* tot = &Ps[16][0] + 68;  // row 17 region (rows 0..15 = red, keep clear gap)
    if (tid < 64) {
        float s = 0.f;
#pragma unroll
        for (int t = 0; t < 16; t++) s += red[t][tid];
        tot[tid] = 1.0f / (s + 1e-8f);
    }
    __syncthreads();
#pragma unroll
    for (int qi = 0; qi < 4; qi++) {
        int qn = q0 + tm * 4 + qi;
        if (qn < N_) {
            float rn = tot[tm * 4 + qi];
            float4 o = make_float4(acc[qi][0] * rn, acc[qi][1] * rn,
                                   acc[qi][2] * rn, acc[qi][3] * rn);
            *(float4*)&context[(size_t)(b * N_ + qn) * C_ + h * D_ + tn * 4] = o;
        }
    }
}

// ---------------------------------------------------------------------------
extern "C" void kernel_launch(void* const* d_in, const int* in_sizes, int n_in,
                              void* d_out, int out_size, void* d_ws, size_t ws_size,
                              hipStream_t stream) {
    const float* x     = (const float*)d_in[0];
    const float* ucb   = (const float*)d_in[1];
    const float* Wqkv  = (const float*)d_in[2];
    const float* Wproj = (const float*)d_in[3];
    const float* bproj = (const float*)d_in[4];
    const int*   counter = (const int*)d_in[5];

    const size_t SZ  = (size_t)B_ * H_ * N_ * D_;  // 7,090,176
    const size_t BHN = (size_t)B_ * H_ * N_;       // 110,784
    float* q        = (float*)d_ws;
    float* k        = q + SZ;
    float* v        = k + SZ;
    float* context  = v + SZ;
    float* w        = context + SZ;
    float* colsum   = w + BHN;
    float* kvmask   = colsum + BHN;
    size_t need = (size_t)(kvmask + (size_t)B_ * N_ - (float*)d_ws) * sizeof(float);
    if (ws_size < need) {
        fprintf(stderr, "kernel_launch: ws too small, need %zu have %zu\n",
                need, ws_size);
        return;
    }

    float* out  = (float*)d_out;
    float* sd   = out + (size_t)B_ * N_ * C_;
    float* kept = sd + (size_t)H_ * N_;

    hipMemsetAsync(kvmask, 0, (size_t)B_ * N_ * sizeof(float), stream);

    gemm_qkv<<<dim3(36, 145), 256, 0, stream>>>(x, Wqkv, q, k, v);
    attn_rowsum<<<dim3(10, B_ * H_), 256, 0, stream>>>(q, k, w);
    attn_colsum2<<<dim3(10, B_ * H_), 256, 0, stream>>>(q, k, w, colsum);
    topk_kernel<<<B_, 512, 0, stream>>>(colsum, ucb, counter, kept, kvmask);
    score_delta_kernel<<<(H_ * N_ + 255) / 256, 256, 0, stream>>>(kvmask, sd);
    attn_ctx<<<dim3(10, B_ * H_), 256, 0, stream>>>(q, k, v, w, kvmask, context);
    gemm_proj<<<dim3(12, 145), 256, 0, stream>>>(context, Wproj, bproj, out);
}

// Round 3
// 853.414 us; speedup vs baseline: 2.2155x; 1.4808x over previous
//
#include <hip/hip_runtime.h>
#include <cstdio>
#include <cstdint>

// Problem constants
#define B_    16
#define N_    577
#define C_    768
#define H_    12
#define D_    64
#define KKEEP 288            // max(1, int(576*0.5))
#define SCALE 0.125f         // 64^-0.5
#define M_TOT (B_ * N_)      // 9232

typedef __bf16 bf16x8_t __attribute__((ext_vector_type(8)));
typedef float  f32x4_t  __attribute__((ext_vector_type(4)));
typedef unsigned int u32x4_t __attribute__((ext_vector_type(4)));

__device__ __forceinline__ f32x4_t mfma_bf16(bf16x8_t a, bf16x8_t b, f32x4_t c) {
    return __builtin_amdgcn_mfma_f32_16x16x32_bf16(a, b, c, 0, 0, 0);
}

// RTZ split of f32 into two bf16 bit patterns (x ~= hi + lo, err ~2^-16 |x|)
__device__ __forceinline__ void splitf(float x, unsigned int &hi, unsigned int &lo) {
    unsigned int u = __float_as_uint(x);
    hi = u >> 16;
    float r = x - __uint_as_float(u & 0xffff0000u);
    lo = __float_as_uint(r) >> 16;
}
__device__ __forceinline__ unsigned int bf16rne(float x) {
    unsigned int u = __float_as_uint(x);
    return (u + 0x7fffu + ((u >> 16) & 1u)) >> 16;
}

// stage 16 f32 (one row-half of a 128x32 K-tile) as split hi/lo bf16 chunks
// into swizzled LDS. sidx = row*32 ushort index, p0/p1 = physical slots.
__device__ __forceinline__ void stage_split(const float* __restrict__ src,
                                            ushort* __restrict__ Hh,
                                            ushort* __restrict__ Hl,
                                            int sidx, int p0, int p1) {
    float4 f0 = *(const float4*)(src);
    float4 f1 = *(const float4*)(src + 4);
    float4 f2 = *(const float4*)(src + 8);
    float4 f3 = *(const float4*)(src + 12);
    unsigned int h[16], l[16];
    splitf(f0.x, h[0], l[0]);  splitf(f0.y, h[1], l[1]);
    splitf(f0.z, h[2], l[2]);  splitf(f0.w, h[3], l[3]);
    splitf(f1.x, h[4], l[4]);  splitf(f1.y, h[5], l[5]);
    splitf(f1.z, h[6], l[6]);  splitf(f1.w, h[7], l[7]);
    splitf(f2.x, h[8], l[8]);  splitf(f2.y, h[9], l[9]);
    splitf(f2.z, h[10], l[10]); splitf(f2.w, h[11], l[11]);
    splitf(f3.x, h[12], l[12]); splitf(f3.y, h[13], l[13]);
    splitf(f3.z, h[14], l[14]); splitf(f3.w, h[15], l[15]);
    u32x4_t hc0 = {h[0] | (h[1] << 16), h[2] | (h[3] << 16),
                   h[4] | (h[5] << 16), h[6] | (h[7] << 16)};
    u32x4_t lc0 = {l[0] | (l[1] << 16), l[2] | (l[3] << 16),
                   l[4] | (l[5] << 16), l[6] | (l[7] << 16)};
    u32x4_t hc1 = {h[8] | (h[9] << 16), h[10] | (h[11] << 16),
                   h[12] | (h[13] << 16), h[14] | (h[15] << 16)};
    u32x4_t lc1 = {l[8] | (l[9] << 16), l[10] | (l[11] << 16),
                   l[12] | (l[13] << 16), l[14] | (l[15] << 16)};
    *(u32x4_t*)&Hh[sidx + p0 * 8] = hc0;
    *(u32x4_t*)&Hl[sidx + p0 * 8] = lc0;
    *(u32x4_t*)&Hh[sidx + p1 * 8] = hc1;
    *(u32x4_t*)&Hl[sidx + p1 * 8] = lc1;
}

// ---------------------------------------------------------------------------
// MFMA GEMM 1 (split precision): qkv = x @ Wqkv^T, scatter to q/k/v f32.
// 128x128 tile, BK=32, 4 waves (2x2), 64x64 per wave, 16x16x32 bf16 MFMA.
// ---------------------------------------------------------------------------
__global__ __launch_bounds__(256) void gemm_qkv_mfma(const float* __restrict__ X,
                                                     const float* __restrict__ W,
                                                     float* __restrict__ qout,
                                                     float* __restrict__ kout,
                                                     float* __restrict__ vout) {
    __shared__ ushort Ah[128 * 32], Al[128 * 32], Bh[128 * 32], Bl[128 * 32];
    const int tid = threadIdx.x;
    const int lane = tid & 63, wave = tid >> 6;
    const int wr = wave >> 1, wc = wave & 1;
    const int lr = lane & 15, ls = lane >> 4;
    const int m0 = blockIdx.y * 128, n0 = blockIdx.x * 128;
    const int srow = tid >> 1, shalf = tid & 1;
    const int arow = min(m0 + srow, M_TOT - 1);
    const float* aptr = X + (size_t)arow * C_ + shalf * 16;
    const float* bptr = W + (size_t)(n0 + srow) * C_ + shalf * 16;
    const int swz = (srow >> 1) & 3;
    const int sidx = srow * 32;
    const int p0 = (shalf * 2 + 0) ^ swz, p1 = (shalf * 2 + 1) ^ swz;
    f32x4_t acc[4][4] = {};
#pragma unroll 1
    for (int k0 = 0; k0 < C_; k0 += 32) {
        __syncthreads();
        stage_split(aptr + k0, Ah, Al, sidx, p0, p1);
        stage_split(bptr + k0, Bh, Bl, sidx, p0, p1);
        __syncthreads();
        bf16x8_t fah[4], fal[4], fbh[4], fbl[4];
#pragma unroll
        for (int i = 0; i < 4; i++) {
            int rowA = wr * 64 + i * 16 + lr;
            int pa = ls ^ ((rowA >> 1) & 3);
            fah[i] = __builtin_bit_cast(bf16x8_t, *(const u32x4_t*)&Ah[rowA * 32 + pa * 8]);
            fal[i] = __builtin_bit_cast(bf16x8_t, *(const u32x4_t*)&Al[rowA * 32 + pa * 8]);
            int rowB = wc * 64 + i * 16 + lr;
            int pb = ls ^ ((rowB >> 1) & 3);
            fbh[i] = __builtin_bit_cast(bf16x8_t, *(const u32x4_t*)&Bh[rowB * 32 + pb * 8]);
            fbl[i] = __builtin_bit_cast(bf16x8_t, *(const u32x4_t*)&Bl[rowB * 32 + pb * 8]);
        }
#pragma unroll
        for (int i = 0; i < 4; i++)
#pragma unroll
            for (int j = 0; j < 4; j++) {
                acc[i][j] = mfma_bf16(fah[i], fbh[j], acc[i][j]);
                acc[i][j] = mfma_bf16(fah[i], fbl[j], acc[i][j]);
                acc[i][j] = mfma_bf16(fal[i], fbh[j], acc[i][j]);
            }
    }
    // epilogue: C row m -> (b,n), col ng -> (q/k/v, h, d); layout [B,H,N,D]
#pragma unroll
    for (int j = 0; j < 4; j++) {
        int ng = n0 + wc * 64 + j * 16 + lr;
        int s = ng / C_;
        int hh = (ng % C_) / D_;
        int d = ng % D_;
        float* dst = (s == 0) ? qout : (s == 1) ? kout : vout;
#pragma unroll
        for (int i = 0; i < 4; i++) {
            int mg0 = m0 + wr * 64 + i * 16 + ls * 4;
#pragma unroll
            for (int r = 0; r < 4; r++) {
                int m = mg0 + r;
                if (m < M_TOT) {
                    int b = m / N_, n = m % N_;
                    dst[(((size_t)(b * H_ + hh) * N_ + n) * D_) + d] = acc[i][j][r];
                }
            }
        }
    }
}

// ---------------------------------------------------------------------------
// MFMA GEMM 2 (plain bf16): out = context_bf16 @ Wproj^T + bproj
// ---------------------------------------------------------------------------
__global__ __launch_bounds__(256) void gemm_proj_mfma(const ushort* __restrict__ Actx,
                                                      const float* __restrict__ W,
                                                      const float* __restrict__ bias,
                                                      float* __restrict__ out) {
    __shared__ ushort Ab[128 * 32], Bb[128 * 32];
    const int tid = threadIdx.x;
    const int lane = tid & 63, wave = tid >> 6;
    const int wr = wave >> 1, wc = wave & 1;
    const int lr = lane & 15, ls = lane >> 4;
    const int m0 = blockIdx.y * 128, n0 = blockIdx.x * 128;
    const int srow = tid >> 1, shalf = tid & 1;
    const int arow = min(m0 + srow, M_TOT - 1);
    const ushort* aptr = Actx + (size_t)arow * C_ + shalf * 16;
    const float* bptr = W + (size_t)(n0 + srow) * C_ + shalf * 16;
    const int swz = (srow >> 1) & 3;
    const int sidx = srow * 32;
    const int p0 = (shalf * 2 + 0) ^ swz, p1 = (shalf * 2 + 1) ^ swz;
    f32x4_t acc[4][4] = {};
#pragma unroll 1
    for (int k0 = 0; k0 < C_; k0 += 32) {
        __syncthreads();
        // A: already bf16, copy through with swizzle
        {
            u32x4_t c0 = *(const u32x4_t*)(aptr + k0);
            u32x4_t c1 = *(const u32x4_t*)(aptr + k0 + 8);
            *(u32x4_t*)&Ab[sidx + p0 * 8] = c0;
            *(u32x4_t*)&Ab[sidx + p1 * 8] = c1;
        }
        // B: f32 -> bf16 RNE
        {
            float4 f0 = *(const float4*)(bptr + k0);
            float4 f1 = *(const float4*)(bptr + k0 + 4);
            float4 f2 = *(const float4*)(bptr + k0 + 8);
            float4 f3 = *(const float4*)(bptr + k0 + 12);
            unsigned int h[16];
            h[0] = bf16rne(f0.x);  h[1] = bf16rne(f0.y);
            h[2] = bf16rne(f0.z);  h[3] = bf16rne(f0.w);
            h[4] = bf16rne(f1.x);  h[5] = bf16rne(f1.y);
            h[6] = bf16rne(f1.z);  h[7] = bf16rne(f1.w);
            h[8] = bf16rne(f2.x);  h[9] = bf16rne(f2.y);
            h[10] = bf16rne(f2.z); h[11] = bf16rne(f2.w);
            h[12] = bf16rne(f3.x); h[13] = bf16rne(f3.y);
            h[14] = bf16rne(f3.z); h[15] = bf16rne(f3.w);
            u32x4_t hc0 = {h[0] | (h[1] << 16), h[2] | (h[3] << 16),
                           h[4] | (h[5] << 16), h[6] | (h[7] << 16)};
            u32x4_t hc1 = {h[8] | (h[9] << 16), h[10] | (h[11] << 16),
                           h[12] | (h[13] << 16), h[14] | (h[15] << 16)};
            *(u32x4_t*)&Bb[sidx + p0 * 8] = hc0;
            *(u32x4_t*)&Bb[sidx + p1 * 8] = hc1;
        }
        __syncthreads();
        bf16x8_t fa[4], fb[4];
#pragma unroll
        for (int i = 0; i < 4; i++) {
            int rowA = wr * 64 + i * 16 + lr;
            int pa = ls ^ ((rowA >> 1) & 3);
            fa[i] = __builtin_bit_cast(bf16x8_t, *(const u32x4_t*)&Ab[rowA * 32 + pa * 8]);
            int rowB = wc * 64 + i * 16 + lr;
            int pb = ls ^ ((rowB >> 1) & 3);
            fb[i] = __builtin_bit_cast(bf16x8_t, *(const u32x4_t*)&Bb[rowB * 32 + pb * 8]);
        }
#pragma unroll
        for (int i = 0; i < 4; i++)
#pragma unroll
            for (int j = 0; j < 4; j++)
                acc[i][j] = mfma_bf16(fa[i], fb[j], acc[i][j]);
    }
#pragma unroll
    for (int j = 0; j < 4; j++) {
        int ng = n0 + wc * 64 + j * 16 + lr;
        float bb = bias[ng];
#pragma unroll
        for (int i = 0; i < 4; i++) {
            int mg0 = m0 + wr * 64 + i * 16 + ls * 4;
#pragma unroll
            for (int r = 0; r < 4; r++) {
                int m = mg0 + r;
                if (m < M_TOT) out[(size_t)m * C_ + ng] = acc[i][j][r] + bb;
            }
        }
    }
}

// ---------------------------------------------------------------------------
// Stage a 64-row x 64-col tile from global [N][64] into LDS TRANSPOSED.
// ---------------------------------------------------------------------------
__device__ __forceinline__ void stage_tile_T(const float* __restrict__ base, int row0,
                                             float (*dst)[68], int tid, float scale) {
    int lrow = tid >> 2, lk4 = (tid & 3) * 16;
    int rn = row0 + lrow;
    bool valid = rn < N_;
    const float* src = base + (size_t)rn * D_ + lk4;
#pragma unroll
    for (int g = 0; g < 4; g++) {
        float4 val = valid ? *(const float4*)(src + g * 4) : make_float4(0.f, 0.f, 0.f, 0.f);
        dst[lk4 + g * 4 + 0][lrow] = val.x * scale;
        dst[lk4 + g * 4 + 1][lrow] = val.y * scale;
        dst[lk4 + g * 4 + 2][lrow] = val.z * scale;
        dst[lk4 + g * 4 + 3][lrow] = val.w * scale;
    }
}

// 4x4 micro-GEMM over the 64-deep d dimension: sacc[qi][jj] += Q.K
__device__ __forceinline__ void smicro(const float (*Qs)[68], const float (*Ks)[68],
                                       int tm, int tn, float sacc[4][4]) {
#pragma unroll 16
    for (int kk = 0; kk < 64; kk++) {
        float a0[4], b0[4];
        *(float4*)a0 = *(const float4*)&Qs[kk][tm * 4];
        *(float4*)b0 = *(const float4*)&Ks[kk][tn * 4];
#pragma unroll
        for (int qi = 0; qi < 4; qi++)
#pragma unroll
            for (int jj = 0; jj < 4; jj++)
                sacc[qi][jj] += a0[qi] * b0[jj];
    }
}

// ---------------------------------------------------------------------------
// Pass R: w[bh][q] = 1 / sum_j exp(scale * q.k)
// ---------------------------------------------------------------------------
__global__ __launch_bounds__(256) void attn_rowsum(const float* __restrict__ q,
                                                   const float* __restrict__ k,
                                                   float* __restrict__ w) {
    int bh = blockIdx.y;
    int q0 = blockIdx.x * 64;
    __shared__ float Qs[64][68];
    __shared__ float Ks[64][68];
    __shared__ float red[16][68];
    int tid = threadIdx.x, tm = tid >> 4, tn = tid & 15;
    const float* qb = q + (size_t)bh * N_ * D_;
    const float* kb = k + (size_t)bh * N_ * D_;
    stage_tile_T(qb, q0, Qs, tid, SCALE);
    float rs[4] = {0.f, 0.f, 0.f, 0.f};
    for (int j0 = 0; j0 < N_; j0 += 64) {
        __syncthreads();
        stage_tile_T(kb, j0, Ks, tid, 1.0f);
        __syncthreads();
        float sacc[4][4] = {};
        smicro(Qs, Ks, tm, tn, sacc);
#pragma unroll
        for (int jj = 0; jj < 4; jj++) {
            int j = j0 + tn * 4 + jj;
            if (j < N_) {
#pragma unroll
                for (int qi = 0; qi < 4; qi++) rs[qi] += __expf(sacc[qi][jj]);
            }
        }
    }
    __syncthreads();
#pragma unroll
    for (int qi = 0; qi < 4; qi++) red[tn][tm * 4 + qi] = rs[qi];
    __syncthreads();
    if (tid < 64) {
        float s = 0.f;
#pragma unroll
        for (int t = 0; t < 16; t++) s += red[t][tid];
        int qn = q0 + tid;
        if (qn < N_) w[(size_t)bh * N_ + qn] = 1.0f / s;
    }
}

// ---------------------------------------------------------------------------
// Pass CS: colsum[bh][j] = sum_q exp(s)*w[q]  (deterministic fixed-order)
// ---------------------------------------------------------------------------
__global__ __launch_bounds__(256) void attn_colsum2(const float* __restrict__ q,
                                                    const float* __restrict__ k,
                                                    const float* __restrict__ w,
                                                    float* __restrict__ colsum) {
    int bh = blockIdx.y;
    int j0 = blockIdx.x * 64;
    __shared__ float Qs[64][68];
    __shared__ float Ks[64][68];
    __shared__ float red[16][68];
    int tid = threadIdx.x, tm = tid >> 4, tn = tid & 15;
    const float* qb = q + (size_t)bh * N_ * D_;
    const float* kb = k + (size_t)bh * N_ * D_;
    stage_tile_T(kb, j0, Ks, tid, SCALE);
    float cs[4] = {0.f, 0.f, 0.f, 0.f};
    for (int qt = 0; qt < N_; qt += 64) {
        __syncthreads();
        stage_tile_T(qb, qt, Qs, tid, 1.0f);
        __syncthreads();
        float sacc[4][4] = {};
        smicro(Qs, Ks, tm, tn, sacc);
        float wv[4];
#pragma unroll
        for (int qi = 0; qi < 4; qi++) {
            int qn = qt + tm * 4 + qi;
            wv[qi] = (qn < N_) ? w[(size_t)bh * N_ + qn] : 0.f;
        }
#pragma unroll
        for (int jj = 0; jj < 4; jj++) {
            int j = j0 + tn * 4 + jj;
            if (j < N_) {
#pragma unroll
                for (int qi = 0; qi < 4; qi++)
                    cs[jj] += __expf(sacc[qi][jj]) * wv[qi];
            }
        }
    }
    __syncthreads();
#pragma unroll
    for (int jj = 0; jj < 4; jj++) red[tm][tn * 4 + jj] = cs[jj];
    __syncthreads();
    if (tid < 64) {
        float s = 0.f;
#pragma unroll
        for (int t = 0; t < 16; t++) s += red[t][tid];
        int j = j0 + tid;
        if (j < N_) colsum[(size_t)bh * N_ + j] = s;
    }
}

// ---------------------------------------------------------------------------
// Top-k per batch: UCB scores + full bitonic sort (desc, ties -> lower index)
// ---------------------------------------------------------------------------
__global__ __launch_bounds__(512) void topk_kernel(const float* __restrict__ colsum,
                                                   const float* __restrict__ ucb_count,
                                                   const int* __restrict__ counter,
                                                   float* __restrict__ kept_out,
                                                   float* __restrict__ kvmask) {
    __shared__ float sv[1024];
    __shared__ int si[1024];
    int b = blockIdx.x, tid = threadIdx.x;
    float lc = logf((float)counter[0] + 1.0f);
    for (int t = tid; t < 1024; t += 512) {
        if (t < N_ - 1) {
            int tok = t + 1;
            float accv = 0.f;
#pragma unroll
            for (int h = 0; h < H_; h++) {
                float csv = colsum[(size_t)(b * H_ + h) * N_ + tok];
                float patch = csv * (1.0f / (float)N_);
                float cnt = ucb_count[h * N_ + tok];
                float expl = sqrtf(lc / (cnt + 1e-6f));
                accv += patch + expl;
            }
            sv[t] = accv * (1.0f / (float)H_);
            si[t] = t;
        } else {
            sv[t] = -INFINITY;
            si[t] = 1 << 20;
        }
    }
    __syncthreads();
    for (int kk = 2; kk <= 1024; kk <<= 1) {
        for (int jj = kk >> 1; jj > 0; jj >>= 1) {
            for (int t = tid; t < 1024; t += 512) {
                int ixj = t ^ jj;
                if (ixj > t) {
                    float v1 = sv[t], v2 = sv[ixj];
                    int i1 = si[t], i2 = si[ixj];
                    bool before21 = (v2 > v1) || (v2 == v1 && i2 < i1);
                    bool dirDesc = ((t & kk) == 0);
                    if (before21 == dirDesc) {
                        sv[t] = v2; sv[ixj] = v1;
                        si[t] = i2; si[ixj] = i1;
                    }
                }
            }
            __syncthreads();
        }
    }
    for (int r = tid; r < KKEEP; r += 512) {
        int tok = si[r] + 1;
        kept_out[b * KKEEP + r] = (float)tok;
        kvmask[b * N_ + tok] = 1.0f;
    }
    if (tid == 0) kvmask[b * N_] = 1.0f;  // CLS always kept
}

// ---------------------------------------------------------------------------
// score_delta[h,n] = (1/B) * count_b(token n kept)   (n=0 -> 0)
// ---------------------------------------------------------------------------
__global__ void score_delta_kernel(const float* __restrict__ kvmask,
                                   float* __restrict__ sd) {
    int idx = blockIdx.x * 256 + threadIdx.x;
    if (idx >= H_ * N_) return;
    int n = idx % N_;
    float d = 0.f;
    if (n != 0) {
#pragma unroll
        for (int b = 0; b < B_; b++) d += kvmask[b * N_ + n];
    }
    sd[idx] = d * (1.0f / (float)B_);
}

// ---------------------------------------------------------------------------
// Pass CTX: masked, renormalized context -> bf16 context [b,n, h*64+d]
// ---------------------------------------------------------------------------
__global__ __launch_bounds__(256) void attn_ctx(const float* __restrict__ q,
                                                const float* __restrict__ k,
                                                const float* __restrict__ v,
                                                const float* __restrict__ w,
                                                const float* __restrict__ kvmask,
                                                ushort* __restrict__ ctxb) {
    int bh = blockIdx.y, b = bh / H_, h = bh % H_;
    int q0 = blockIdx.x * 64;
    __shared__ float Qs[64][68];
    __shared__ float KVs[64][68];
    __shared__ float Ps[64][68];
    int tid = threadIdx.x, tm = tid >> 4, tn = tid & 15;
    const float* qb = q + (size_t)bh * N_ * D_;
    const float* kb = k + (size_t)bh * N_ * D_;
    const float* vb = v + (size_t)bh * N_ * D_;
    stage_tile_T(qb, q0, Qs, tid, SCALE);
    float wv[4], mq[4];
#pragma unroll
    for (int qi = 0; qi < 4; qi++) {
        int qn = q0 + tm * 4 + qi;
        wv[qi] = (qn < N_) ? w[(size_t)bh * N_ + qn] : 0.f;
        mq[qi] = (qn < N_) ? kvmask[b * N_ + qn] : 0.f;
    }
    float acc[4][4] = {};
    float ps[4] = {0.f, 0.f, 0.f, 0.f};
    int lrow = tid >> 2, lk4 = (tid & 3) * 16;
    for (int j0 = 0; j0 < N_; j0 += 64) {
        __syncthreads();
        stage_tile_T(kb, j0, KVs, tid, 1.0f);
        __syncthreads();
        float sacc[4][4] = {};
        smicro(Qs, KVs, tm, tn, sacc);
        float4 pr[4];
#pragma unroll
        for (int jj = 0; jj < 4; jj++) {
            int j = j0 + tn * 4 + jj;
            float mj = (j < N_) ? kvmask[b * N_ + j] : 0.f;
            float pv[4];
#pragma unroll
            for (int qi = 0; qi < 4; qi++) {
                float p = (j < N_) ? __expf(sacc[qi][jj]) * wv[qi] : 0.f;
                if (!(mq[qi] > 0.5f || mj > 0.5f)) p = 0.f;
                pv[qi] = p;
                ps[qi] += p;
            }
            pr[jj] = make_float4(pv[0], pv[1], pv[2], pv[3]);
        }
        __syncthreads();
        {
            int jn = j0 + lrow;
            bool vvok = jn < N_;
            const float* src = vb + (size_t)jn * D_ + lk4;
#pragma unroll
            for (int g = 0; g < 4; g++) {
                float4 val = vvok ? *(const float4*)(src + g * 4)
                                  : make_float4(0.f, 0.f, 0.f, 0.f);
                *(float4*)&KVs[lrow][lk4 + g * 4] = val;
            }
        }
#pragma unroll
        for (int jj = 0; jj < 4; jj++)
            *(float4*)&Ps[tn * 4 + jj][tm * 4] = pr[jj];
        __syncthreads();
#pragma unroll 16
        for (int jj2 = 0; jj2 < 64; jj2++) {
            float a0[4], b0[4];
            *(float4*)a0 = *(const float4*)&Ps[jj2][tm * 4];
            *(float4*)b0 = *(const float4*)&KVs[jj2][tn * 4];
#pragma unroll
            for (int qi = 0; qi < 4; qi++)
#pragma unroll
                for (int di = 0; di < 4; di++)
                    acc[qi][di] += a0[qi] * b0[di];
        }
    }
    __syncthreads();
    float (*red)[68] = (float(*)[68])Ps;
#pragma unroll
    for (int qi = 0; qi < 4; qi++) red[tn][tm * 4 + qi] = ps[qi];
    __syncthreads();
    float* tot = &Ps[16][0] + 68;
    if (tid < 64) {
        float s = 0.f;
#pragma unroll
        for (int t = 0; t < 16; t++) s += red[t][tid];
        tot[tid] = 1.0f / (s + 1e-8f);
    }
    __syncthreads();
#pragma unroll
    for (int qi = 0; qi < 4; qi++) {
        int qn = q0 + tm * 4 + qi;
        if (qn < N_) {
            float rn = tot[tm * 4 + qi];
            unsigned int h0 = bf16rne(acc[qi][0] * rn);
            unsigned int h1 = bf16rne(acc[qi][1] * rn);
            unsigned int h2 = bf16rne(acc[qi][2] * rn);
            unsigned int h3 = bf16rne(acc[qi][3] * rn);
            uint2 pk = make_uint2(h0 | (h1 << 16), h2 | (h3 << 16));
            *(uint2*)&ctxb[(size_t)(b * N_ + qn) * C_ + h * D_ + tn * 4] = pk;
        }
    }
}

// ---------------------------------------------------------------------------
extern "C" void kernel_launch(void* const* d_in, const int* in_sizes, int n_in,
                              void* d_out, int out_size, void* d_ws, size_t ws_size,
                              hipStream_t stream) {
    const float* x     = (const float*)d_in[0];
    const float* ucb   = (const float*)d_in[1];
    const float* Wqkv  = (const float*)d_in[2];
    const float* Wproj = (const float*)d_in[3];
    const float* bproj = (const float*)d_in[4];
    const int*   counter = (const int*)d_in[5];

    const size_t SZ  = (size_t)B_ * H_ * N_ * D_;  // 7,090,176
    const size_t BHN = (size_t)B_ * H_ * N_;       // 110,784
    float* q        = (float*)d_ws;
    float* k        = q + SZ;
    float* v        = k + SZ;
    float* w        = v + SZ;
    float* colsum   = w + BHN;
    float* kvmask   = colsum + BHN;
    ushort* ctxb    = (ushort*)(kvmask + (size_t)B_ * N_);
    size_t need = ((char*)(ctxb + SZ)) - (char*)d_ws;
    if (ws_size < need) {
        fprintf(stderr, "kernel_launch: ws too small, need %zu have %zu\n",
                need, ws_size);
        return;
    }

    float* out  = (float*)d_out;
    float* sd   = out + (size_t)B_ * N_ * C_;
    float* kept = sd + (size_t)H_ * N_;

    hipMemsetAsync(kvmask, 0, (size_t)B_ * N_ * sizeof(float), stream);

    gemm_qkv_mfma<<<dim3(18, 73), 256, 0, stream>>>(x, Wqkv, q, k, v);
    attn_rowsum<<<dim3(10, B_ * H_), 256, 0, stream>>>(q, k, w);
    attn_colsum2<<<dim3(10, B_ * H_), 256, 0, stream>>>(q, k, w, colsum);
    topk_kernel<<<B_, 512, 0, stream>>>(colsum, ucb, counter, kept, kvmask);
    score_delta_kernel<<<(H_ * N_ + 255) / 256, 256, 0, stream>>>(kvmask, sd);
    attn_ctx<<<dim3(10, B_ * H_), 256, 0, stream>>>(q, k, v, w, kvmask, ctxb);
    gemm_proj_mfma<<<dim3(6, 73), 256, 0, stream>>>(ctxb, Wproj, bproj, out);
}

// Round 4
// 404.749 us; speedup vs baseline: 4.6714x; 2.1085x over previous
//
#include <hip/hip_runtime.h>
#include <cstdio>
#include <cstdint>

// Problem constants
#define B_    16
#define N_    577
#define C_    768
#define H_    12
#define D_    64
#define KKEEP 288            // max(1, int(576*0.5))
#define SCALE 0.125f         // 64^-0.5
#define M_TOT (B_ * N_)      // 9232
#define VTS   640            // vt row stride (>= 10*64, 16B-aligned)

typedef __bf16 bf16x8_t __attribute__((ext_vector_type(8)));
typedef float  f32x4_t  __attribute__((ext_vector_type(4)));
typedef unsigned int u32x4_t __attribute__((ext_vector_type(4)));

__device__ __forceinline__ f32x4_t mfma_bf16(bf16x8_t a, bf16x8_t b, f32x4_t c) {
    return __builtin_amdgcn_mfma_f32_16x16x32_bf16(a, b, c, 0, 0, 0);
}

// RTZ split of f32 into two bf16 bit patterns (x ~= hi + lo, err ~2^-16 |x|)
__device__ __forceinline__ void splitf(float x, unsigned int &hi, unsigned int &lo) {
    unsigned int u = __float_as_uint(x);
    hi = u >> 16;
    float r = x - __uint_as_float(u & 0xffff0000u);
    lo = __float_as_uint(r) >> 16;
}
__device__ __forceinline__ unsigned int bf16rne(float x) {
    unsigned int u = __float_as_uint(x);
    return (u + 0x7fffu + ((u >> 16) & 1u)) >> 16;
}

// ===========================================================================
// 64x64 bf16 LDS tiles: 64 ushort/row, 8 slots of 8; phys slot = logical^(row&7)
// fragT: read MFMA fragment (row, k-chunk c: k = c*32 + ls*8 .. +7)
// ===========================================================================
__device__ __forceinline__ bf16x8_t fragT(const ushort* H, int row, int c, int ls) {
    int phys = ((c << 2) + ls) ^ (row & 7);
    return __builtin_bit_cast(bf16x8_t, *(const u32x4_t*)&H[(row << 6) + (phys << 3)]);
}

// stage 64x64 f32 tile (rows row0.. from [N][64] f32) as split hi/lo bf16
__device__ __forceinline__ void stage_split64(const float* __restrict__ base, int row0,
                                              float scale, ushort* Hh, ushort* Hl, int tid) {
    int r = tid >> 2, qd = tid & 3;
    int rn = row0 + r;
    float f[16];
    if (rn < N_) {
        const float* src = base + (size_t)rn * D_ + qd * 16;
        *(float4*)&f[0]  = *(const float4*)(src);
        *(float4*)&f[4]  = *(const float4*)(src + 4);
        *(float4*)&f[8]  = *(const float4*)(src + 8);
        *(float4*)&f[12] = *(const float4*)(src + 12);
    } else {
#pragma unroll
        for (int i = 0; i < 16; i++) f[i] = 0.f;
    }
    unsigned int h[16], l[16];
#pragma unroll
    for (int i = 0; i < 16; i++) splitf(f[i] * scale, h[i], l[i]);
    u32x4_t hc0 = {h[0] | (h[1] << 16), h[2] | (h[3] << 16),
                   h[4] | (h[5] << 16), h[6] | (h[7] << 16)};
    u32x4_t hc1 = {h[8] | (h[9] << 16), h[10] | (h[11] << 16),
                   h[12] | (h[13] << 16), h[14] | (h[15] << 16)};
    u32x4_t lc0 = {l[0] | (l[1] << 16), l[2] | (l[3] << 16),
                   l[4] | (l[5] << 16), l[6] | (l[7] << 16)};
    u32x4_t lc1 = {l[8] | (l[9] << 16), l[10] | (l[11] << 16),
                   l[12] | (l[13] << 16), l[14] | (l[15] << 16)};
    int s0 = (2 * qd) ^ (r & 7), s1 = (2 * qd + 1) ^ (r & 7);
    *(u32x4_t*)&Hh[(r << 6) + (s0 << 3)] = hc0;
    *(u32x4_t*)&Hh[(r << 6) + (s1 << 3)] = hc1;
    *(u32x4_t*)&Hl[(r << 6) + (s0 << 3)] = lc0;
    *(u32x4_t*)&Hl[(r << 6) + (s1 << 3)] = lc1;
}

// stage 64x64 bf16 tile from vt (rows = d, row stride VTS), cols j0..j0+63
__device__ __forceinline__ void stage_vt(const ushort* __restrict__ vtb, int j0,
                                         ushort* Vt, int tid) {
    int r = tid >> 2, qd = tid & 3;
    const ushort* src = vtb + (size_t)r * VTS + j0 + qd * 16;
    u32x4_t c0 = *(const u32x4_t*)(src);
    u32x4_t c1 = *(const u32x4_t*)(src + 8);
    int s0 = (2 * qd) ^ (r & 7), s1 = (2 * qd + 1) ^ (r & 7);
    *(u32x4_t*)&Vt[(r << 6) + (s0 << 3)] = c0;
    *(u32x4_t*)&Vt[(r << 6) + (s1 << 3)] = c1;
}

// ---------------------------------------------------------------------------
// MFMA GEMM 1 (split precision): qkv = x @ Wqkv^T; q,k f32 [B,H,N,D]; v bf16.
// ---------------------------------------------------------------------------
__global__ __launch_bounds__(256) void gemm_qkv_mfma(const float* __restrict__ X,
                                                     const float* __restrict__ W,
                                                     float* __restrict__ qout,
                                                     float* __restrict__ kout,
                                                     ushort* __restrict__ vout) {
    __shared__ ushort Ah[128 * 32], Al[128 * 32], Bh[128 * 32], Bl[128 * 32];
    const int tid = threadIdx.x;
    const int lane = tid & 63, wave = tid >> 6;
    const int wr = wave >> 1, wc = wave & 1;
    const int lr = lane & 15, ls = lane >> 4;
    const int m0 = blockIdx.y * 128, n0 = blockIdx.x * 128;
    const int srow = tid >> 1, shalf = tid & 1;
    const int arow = min(m0 + srow, M_TOT - 1);
    const float* aptr = X + (size_t)arow * C_ + shalf * 16;
    const float* bptr = W + (size_t)(n0 + srow) * C_ + shalf * 16;
    const int swz = (srow >> 1) & 3;
    const int sidx = srow * 32;
    const int p0 = (shalf * 2 + 0) ^ swz, p1 = (shalf * 2 + 1) ^ swz;
    f32x4_t acc[4][4] = {};
#pragma unroll 1
    for (int k0 = 0; k0 < C_; k0 += 32) {
        __syncthreads();
        {
            float4 f0 = *(const float4*)(aptr + k0);
            float4 f1 = *(const float4*)(aptr + k0 + 4);
            float4 f2 = *(const float4*)(aptr + k0 + 8);
            float4 f3 = *(const float4*)(aptr + k0 + 12);
            unsigned int h[16], l[16];
            splitf(f0.x, h[0], l[0]);   splitf(f0.y, h[1], l[1]);
            splitf(f0.z, h[2], l[2]);   splitf(f0.w, h[3], l[3]);
            splitf(f1.x, h[4], l[4]);   splitf(f1.y, h[5], l[5]);
            splitf(f1.z, h[6], l[6]);   splitf(f1.w, h[7], l[7]);
            splitf(f2.x, h[8], l[8]);   splitf(f2.y, h[9], l[9]);
            splitf(f2.z, h[10], l[10]); splitf(f2.w, h[11], l[11]);
            splitf(f3.x, h[12], l[12]); splitf(f3.y, h[13], l[13]);
            splitf(f3.z, h[14], l[14]); splitf(f3.w, h[15], l[15]);
            u32x4_t hc0 = {h[0] | (h[1] << 16), h[2] | (h[3] << 16),
                           h[4] | (h[5] << 16), h[6] | (h[7] << 16)};
            u32x4_t hc1 = {h[8] | (h[9] << 16), h[10] | (h[11] << 16),
                           h[12] | (h[13] << 16), h[14] | (h[15] << 16)};
            u32x4_t lc0 = {l[0] | (l[1] << 16), l[2] | (l[3] << 16),
                           l[4] | (l[5] << 16), l[6] | (l[7] << 16)};
            u32x4_t lc1 = {l[8] | (l[9] << 16), l[10] | (l[11] << 16),
                           l[12] | (l[13] << 16), l[14] | (l[15] << 16)};
            *(u32x4_t*)&Ah[sidx + p0 * 8] = hc0;
            *(u32x4_t*)&Ah[sidx + p1 * 8] = hc1;
            *(u32x4_t*)&Al[sidx + p0 * 8] = lc0;
            *(u32x4_t*)&Al[sidx + p1 * 8] = lc1;
        }
        {
            float4 f0 = *(const float4*)(bptr + k0);
            float4 f1 = *(const float4*)(bptr + k0 + 4);
            float4 f2 = *(const float4*)(bptr + k0 + 8);
            float4 f3 = *(const float4*)(bptr + k0 + 12);
            unsigned int h[16], l[16];
            splitf(f0.x, h[0], l[0]);   splitf(f0.y, h[1], l[1]);
            splitf(f0.z, h[2], l[2]);   splitf(f0.w, h[3], l[3]);
            splitf(f1.x, h[4], l[4]);   splitf(f1.y, h[5], l[5]);
            splitf(f1.z, h[6], l[6]);   splitf(f1.w, h[7], l[7]);
            splitf(f2.x, h[8], l[8]);   splitf(f2.y, h[9], l[9]);
            splitf(f2.z, h[10], l[10]); splitf(f2.w, h[11], l[11]);
            splitf(f3.x, h[12], l[12]); splitf(f3.y, h[13], l[13]);
            splitf(f3.z, h[14], l[14]); splitf(f3.w, h[15], l[15]);
            u32x4_t hc0 = {h[0] | (h[1] << 16), h[2] | (h[3] << 16),
                           h[4] | (h[5] << 16), h[6] | (h[7] << 16)};
            u32x4_t hc1 = {h[8] | (h[9] << 16), h[10] | (h[11] << 16),
                           h[12] | (h[13] << 16), h[14] | (h[15] << 16)};
            u32x4_t lc0 = {l[0] | (l[1] << 16), l[2] | (l[3] << 16),
                           l[4] | (l[5] << 16), l[6] | (l[7] << 16)};
            u32x4_t lc1 = {l[8] | (l[9] << 16), l[10] | (l[11] << 16),
                           l[12] | (l[13] << 16), l[14] | (l[15] << 16)};
            *(u32x4_t*)&Bh[sidx + p0 * 8] = hc0;
            *(u32x4_t*)&Bh[sidx + p1 * 8] = hc1;
            *(u32x4_t*)&Bl[sidx + p0 * 8] = lc0;
            *(u32x4_t*)&Bl[sidx + p1 * 8] = lc1;
        }
        __syncthreads();
        bf16x8_t fah[4], fal[4], fbh[4], fbl[4];
#pragma unroll
        for (int i = 0; i < 4; i++) {
            int rowA = wr * 64 + i * 16 + lr;
            int pa = ls ^ ((rowA >> 1) & 3);
            fah[i] = __builtin_bit_cast(bf16x8_t, *(const u32x4_t*)&Ah[rowA * 32 + pa * 8]);
            fal[i] = __builtin_bit_cast(bf16x8_t, *(const u32x4_t*)&Al[rowA * 32 + pa * 8]);
            int rowB = wc * 64 + i * 16 + lr;
            int pb = ls ^ ((rowB >> 1) & 3);
            fbh[i] = __builtin_bit_cast(bf16x8_t, *(const u32x4_t*)&Bh[rowB * 32 + pb * 8]);
            fbl[i] = __builtin_bit_cast(bf16x8_t, *(const u32x4_t*)&Bl[rowB * 32 + pb * 8]);
        }
#pragma unroll
        for (int i = 0; i < 4; i++)
#pragma unroll
            for (int j = 0; j < 4; j++) {
                acc[i][j] = mfma_bf16(fah[i], fbh[j], acc[i][j]);
                acc[i][j] = mfma_bf16(fah[i], fbl[j], acc[i][j]);
                acc[i][j] = mfma_bf16(fal[i], fbh[j], acc[i][j]);
            }
    }
    const int s = n0 / C_;  // 0=q, 1=k, 2=v (128 | 768, block-uniform)
#pragma unroll
    for (int j = 0; j < 4; j++) {
        int ng = n0 + wc * 64 + j * 16 + lr;
        int hh = (ng % C_) / D_;
        int d = ng % D_;
#pragma unroll
        for (int i = 0; i < 4; i++) {
            int mg0 = m0 + wr * 64 + i * 16 + ls * 4;
#pragma unroll
            for (int r = 0; r < 4; r++) {
                int m = mg0 + r;
                if (m < M_TOT) {
                    int b = m / N_, n = m % N_;
                    size_t idx = (((size_t)(b * H_ + hh) * N_ + n) * D_) + d;
                    if (s == 2) vout[idx] = (ushort)bf16rne(acc[i][j][r]);
                    else if (s == 1) kout[idx] = acc[i][j][r];
                    else qout[idx] = acc[i][j][r];
                }
            }
        }
    }
}

// ---------------------------------------------------------------------------
// V transpose: vb16 [bh][n][64] bf16 -> vt [bh*64 + d][VTS] bf16 (cols = n)
// ---------------------------------------------------------------------------
__global__ __launch_bounds__(256) void vtrans_kernel(const ushort* __restrict__ vb,
                                                     ushort* __restrict__ vt) {
    int bh = blockIdx.y, n0 = blockIdx.x * 64;
    __shared__ ushort T[64 * 64];   // swizzled like fragT tiles
    int tid = threadIdx.x;
    int r = tid >> 2, qd = tid & 3;
    int n = n0 + r;
    u32x4_t c0 = {0, 0, 0, 0}, c1 = {0, 0, 0, 0};
    if (n < N_) {
        const ushort* src = vb + ((size_t)bh * N_ + n) * D_ + qd * 16;
        c0 = *(const u32x4_t*)(src);
        c1 = *(const u32x4_t*)(src + 8);
    }
    int s0 = (2 * qd) ^ (r & 7), s1 = (2 * qd + 1) ^ (r & 7);
    *(u32x4_t*)&T[(r << 6) + (s0 << 3)] = c0;
    *(u32x4_t*)&T[(r << 6) + (s1 << 3)] = c1;
    __syncthreads();
    // out row d = r, cols n0 + qd*16 .. +15 ; value = T[row=qd*16+i][col=r]
    unsigned int o[16];
#pragma unroll
    for (int i = 0; i < 16; i++) {
        int row = qd * 16 + i;
        int phys = ((r >> 3) ^ (row & 7));
        o[i] = T[(row << 6) + (phys << 3) + (r & 7)];
    }
    u32x4_t w0 = {o[0] | (o[1] << 16), o[2] | (o[3] << 16),
                  o[4] | (o[5] << 16), o[6] | (o[7] << 16)};
    u32x4_t w1 = {o[8] | (o[9] << 16), o[10] | (o[11] << 16),
                  o[12] | (o[13] << 16), o[14] | (o[15] << 16)};
    ushort* dst = vt + ((size_t)bh * 64 + r) * VTS + n0 + qd * 16;
    *(u32x4_t*)(dst) = w0;
    *(u32x4_t*)(dst + 8) = w1;
}

// ---------------------------------------------------------------------------
// Pass R: w[bh][q] = 1 / sum_j exp(scale*q.k)   (swapped S^T MFMA, split)
// ---------------------------------------------------------------------------
__global__ __launch_bounds__(256) void attn_rowsum_mfma(const float* __restrict__ q,
                                                        const float* __restrict__ k,
                                                        float* __restrict__ w) {
    __shared__ ushort Qh[4096], Ql[4096], Kh[4096], Kl[4096];
    __shared__ float red[4][64];
    int bh = blockIdx.y, q0 = blockIdx.x * 64;
    int tid = threadIdx.x, lane = tid & 63, wv = tid >> 6;
    int lr = lane & 15, ls = lane >> 4;
    const float* qb = q + (size_t)bh * N_ * D_;
    const float* kb = k + (size_t)bh * N_ * D_;
    stage_split64(qb, q0, SCALE, Qh, Ql, tid);
    __syncthreads();
    bf16x8_t fqh[4][2], fql[4][2];   // B operand: n = q = i*16+lr
#pragma unroll
    for (int i = 0; i < 4; i++)
#pragma unroll
        for (int c = 0; c < 2; c++) {
            fqh[i][c] = fragT(Qh, i * 16 + lr, c, ls);
            fql[i][c] = fragT(Ql, i * 16 + lr, c, ls);
        }
    float rs[4] = {0.f, 0.f, 0.f, 0.f};
    for (int j0 = 0; j0 < N_; j0 += 64) {
        __syncthreads();
        stage_split64(kb, j0, 1.0f, Kh, Kl, tid);
        __syncthreads();
        bf16x8_t fkh[2], fkl[2];     // A operand: m = j = wv*16+lr
#pragma unroll
        for (int c = 0; c < 2; c++) {
            fkh[c] = fragT(Kh, wv * 16 + lr, c, ls);
            fkl[c] = fragT(Kl, wv * 16 + lr, c, ls);
        }
        int jbase = j0 + wv * 16 + ls * 4;
#pragma unroll
        for (int i = 0; i < 4; i++) {
            f32x4_t s = {0.f, 0.f, 0.f, 0.f};
#pragma unroll
            for (int c = 0; c < 2; c++) {
                s = mfma_bf16(fkh[c], fqh[i][c], s);
                s = mfma_bf16(fkh[c], fql[i][c], s);
                s = mfma_bf16(fkl[c], fqh[i][c], s);
            }
#pragma unroll
            for (int r = 0; r < 4; r++)
                rs[i] += (jbase + r < N_) ? __expf(s[r]) : 0.f;
        }
    }
#pragma unroll
    for (int i = 0; i < 4; i++) {
        float v2 = rs[i];
        v2 += __shfl_xor(v2, 16);
        v2 += __shfl_xor(v2, 32);
        if (ls == 0) red[wv][i * 16 + lr] = v2;
    }
    __syncthreads();
    if (tid < 64) {
        float s = red[0][tid] + red[1][tid] + red[2][tid] + red[3][tid];
        int qn = q0 + tid;
        if (qn < N_) w[(size_t)bh * N_ + qn] = 1.0f / s;
    }
}

// ---------------------------------------------------------------------------
// Pass CS: colsum[bh][j] = sum_q exp(s)*w[q]   (natural S MFMA, split)
// ---------------------------------------------------------------------------
__global__ __launch_bounds__(256) void attn_colsum_mfma(const float* __restrict__ q,
                                                        const float* __restrict__ k,
                                                        const float* __restrict__ w,
                                                        float* __restrict__ colsum) {
    __shared__ ushort Qh[4096], Ql[4096], Kh[4096], Kl[4096];
    __shared__ float red[4][64];
    __shared__ float wsld[64];
    int bh = blockIdx.y, j0 = blockIdx.x * 64;
    int tid = threadIdx.x, lane = tid & 63, wv = tid >> 6;
    int lr = lane & 15, ls = lane >> 4;
    const float* qb = q + (size_t)bh * N_ * D_;
    const float* kb = k + (size_t)bh * N_ * D_;
    stage_split64(kb, j0, SCALE, Kh, Kl, tid);
    __syncthreads();
    bf16x8_t fkh[4][2], fkl[4][2];   // B operand: n = j = i*16+lr
#pragma unroll
    for (int i = 0; i < 4; i++)
#pragma unroll
        for (int c = 0; c < 2; c++) {
            fkh[i][c] = fragT(Kh, i * 16 + lr, c, ls);
            fkl[i][c] = fragT(Kl, i * 16 + lr, c, ls);
        }
    float cs[4] = {0.f, 0.f, 0.f, 0.f};
    for (int qt = 0; qt < N_; qt += 64) {
        __syncthreads();
        stage_split64(qb, qt, 1.0f, Qh, Ql, tid);
        if (tid < 64) {
            int qn = qt + tid;
            wsld[tid] = (qn < N_) ? w[(size_t)bh * N_ + qn] : 0.f;
        }
        __syncthreads();
        bf16x8_t fqh[2], fql[2];     // A operand: m = q = wv*16+lr
#pragma unroll
        for (int c = 0; c < 2; c++) {
            fqh[c] = fragT(Qh, wv * 16 + lr, c, ls);
            fql[c] = fragT(Ql, wv * 16 + lr, c, ls);
        }
        float wq[4];
#pragma unroll
        for (int r = 0; r < 4; r++) wq[r] = wsld[wv * 16 + ls * 4 + r];
#pragma unroll
        for (int i = 0; i < 4; i++) {
            f32x4_t s = {0.f, 0.f, 0.f, 0.f};
#pragma unroll
            for (int c = 0; c < 2; c++) {
                s = mfma_bf16(fqh[c], fkh[i][c], s);
                s = mfma_bf16(fql[c], fkh[i][c], s);
                s = mfma_bf16(fqh[c], fkl[i][c], s);
            }
#pragma unroll
            for (int r = 0; r < 4; r++) cs[i] += __expf(s[r]) * wq[r];
        }
    }
#pragma unroll
    for (int i = 0; i < 4; i++) {
        float v2 = cs[i];
        v2 += __shfl_xor(v2, 16);
        v2 += __shfl_xor(v2, 32);
        if (ls == 0) red[wv][i * 16 + lr] = v2;
    }
    __syncthreads();
    if (tid < 64) {
        float t = red[0][tid] + red[1][tid] + red[2][tid] + red[3][tid];
        int jn = j0 + tid;
        if (jn < N_) colsum[(size_t)bh * N_ + jn] = t;
    }
}

// ---------------------------------------------------------------------------
// Top-k per batch: UCB scores + full bitonic sort (desc, ties -> lower index)
// ---------------------------------------------------------------------------
__global__ __launch_bounds__(512) void topk_kernel(const float* __restrict__ colsum,
                                                   const float* __restrict__ ucb_count,
                                                   const int* __restrict__ counter,
                                                   float* __restrict__ kept_out,
                                                   float* __restrict__ kvmask) {
    __shared__ float sv[1024];
    __shared__ int si[1024];
    int b = blockIdx.x, tid = threadIdx.x;
    float lc = logf((float)counter[0] + 1.0f);
    for (int t = tid; t < 1024; t += 512) {
        if (t < N_ - 1) {
            int tok = t + 1;
            float accv = 0.f;
#pragma unroll
            for (int h = 0; h < H_; h++) {
                float csv = colsum[(size_t)(b * H_ + h) * N_ + tok];
                float patch = csv * (1.0f / (float)N_);
                float cnt = ucb_count[h * N_ + tok];
                float expl = sqrtf(lc / (cnt + 1e-6f));
                accv += patch + expl;
            }
            sv[t] = accv * (1.0f / (float)H_);
            si[t] = t;
        } else {
            sv[t] = -INFINITY;
            si[t] = 1 << 20;
        }
    }
    __syncthreads();
    for (int kk = 2; kk <= 1024; kk <<= 1) {
        for (int jj = kk >> 1; jj > 0; jj >>= 1) {
            for (int t = tid; t < 1024; t += 512) {
                int ixj = t ^ jj;
                if (ixj > t) {
                    float v1 = sv[t], v2 = sv[ixj];
                    int i1 = si[t], i2 = si[ixj];
                    bool before21 = (v2 > v1) || (v2 == v1 && i2 < i1);
                    bool dirDesc = ((t & kk) == 0);
                    if (before21 == dirDesc) {
                        sv[t] = v2; sv[ixj] = v1;
                        si[t] = i2; si[ixj] = i1;
                    }
                }
            }
            __syncthreads();
        }
    }
    for (int r = tid; r < KKEEP; r += 512) {
        int tok = si[r] + 1;
        kept_out[b * KKEEP + r] = (float)tok;
        kvmask[b * N_ + tok] = 1.0f;
    }
    if (tid == 0) kvmask[b * N_] = 1.0f;  // CLS always kept
}

// ---------------------------------------------------------------------------
// score_delta[h,n] = (1/B) * count_b(token n kept)   (n=0 -> 0)
// ---------------------------------------------------------------------------
__global__ void score_delta_kernel(const float* __restrict__ kvmask,
                                   float* __restrict__ sd) {
    int idx = blockIdx.x * 256 + threadIdx.x;
    if (idx >= H_ * N_) return;
    int n = idx % N_;
    float d = 0.f;
    if (n != 0) {
#pragma unroll
        for (int b = 0; b < B_; b++) d += kvmask[b * N_ + n];
    }
    sd[idx] = d * (1.0f / (float)B_);
}

// ---------------------------------------------------------------------------
// Pass CTX: masked renormalized context -> bf16 [b,n, h*64+d]
// S^T = mfma(K,Q) split; P packed bf16 to LDS [q][j]; PV = mfma(Vt, P).
// ---------------------------------------------------------------------------
__global__ __launch_bounds__(256) void attn_ctx_mfma(const float* __restrict__ q,
                                                     const float* __restrict__ k,
                                                     const ushort* __restrict__ vt,
                                                     const float* __restrict__ w,
                                                     const float* __restrict__ kvmask,
                                                     ushort* __restrict__ ctxb) {
    __shared__ ushort Qh[4096], Ql[4096], Kh[4096], Kl[4096], Vt[4096], Pl[4096];
    __shared__ float wsld[64], mqs[64], mjs[64], red[4][64], inv[64];
    int bh = blockIdx.y, b = bh / H_, h = bh % H_;
    int q0 = blockIdx.x * 64;
    int tid = threadIdx.x, lane = tid & 63, wv = tid >> 6;
    int lr = lane & 15, ls = lane >> 4;
    const float* qbase = q + (size_t)bh * N_ * D_;
    const float* kbase = k + (size_t)bh * N_ * D_;
    const ushort* vtb = vt + (size_t)bh * 64 * VTS;
    stage_split64(qbase, q0, SCALE, Qh, Ql, tid);
    if (tid < 64) {
        int qn = q0 + tid;
        wsld[tid] = (qn < N_) ? w[(size_t)bh * N_ + qn] : 0.f;
        mqs[tid]  = (qn < N_) ? kvmask[b * N_ + qn] : 0.f;
    }
    __syncthreads();
    bf16x8_t fqh[4][2], fql[4][2];
#pragma unroll
    for (int i = 0; i < 4; i++)
#pragma unroll
        for (int c = 0; c < 2; c++) {
            fqh[i][c] = fragT(Qh, i * 16 + lr, c, ls);
            fql[i][c] = fragT(Ql, i * 16 + lr, c, ls);
        }
    float wq[4], mq[4];
#pragma unroll
    for (int i = 0; i < 4; i++) { wq[i] = wsld[i * 16 + lr]; mq[i] = mqs[i * 16 + lr]; }
    f32x4_t acc[4] = {};
    float psums[4] = {0.f, 0.f, 0.f, 0.f};
    for (int j0t = 0; j0t < N_; j0t += 64) {
        __syncthreads();
        stage_split64(kbase, j0t, 1.0f, Kh, Kl, tid);
        stage_vt(vtb, j0t, Vt, tid);
        if (tid < 64) {
            int jn = j0t + tid;
            mjs[tid] = (jn < N_) ? kvmask[b * N_ + jn] : 0.f;
        }
        __syncthreads();
        bf16x8_t fkh[2], fkl[2];
#pragma unroll
        for (int c = 0; c < 2; c++) {
            fkh[c] = fragT(Kh, wv * 16 + lr, c, ls);
            fkl[c] = fragT(Kl, wv * 16 + lr, c, ls);
        }
        int jloc = wv * 16 + ls * 4;
#pragma unroll
        for (int i = 0; i < 4; i++) {
            f32x4_t s = {0.f, 0.f, 0.f, 0.f};
#pragma unroll
            for (int c = 0; c < 2; c++) {
                s = mfma_bf16(fkh[c], fqh[i][c], s);
                s = mfma_bf16(fkh[c], fql[i][c], s);
                s = mfma_bf16(fkl[c], fqh[i][c], s);
            }
            unsigned int pk[4];
            float wqi = wq[i], mqi = mq[i];
#pragma unroll
            for (int r = 0; r < 4; r++) {
                int j = j0t + jloc + r;
                float mj = mjs[jloc + r];
                float p = (j < N_) ? __expf(s[r]) * wqi : 0.f;
                p = (mqi > 0.5f || mj > 0.5f) ? p : 0.f;
                psums[i] += p;
                pk[r] = bf16rne(p);
            }
            int row = i * 16 + lr;
            int slot = ((wv << 1) + (ls >> 1)) ^ (row & 7);
            *(uint2*)&Pl[(row << 6) + (slot << 3) + ((ls & 1) << 2)] =
                make_uint2(pk[0] | (pk[1] << 16), pk[2] | (pk[3] << 16));
        }
        __syncthreads();
        bf16x8_t fv[2];
#pragma unroll
        for (int c = 0; c < 2; c++) fv[c] = fragT(Vt, wv * 16 + lr, c, ls);
#pragma unroll
        for (int i = 0; i < 4; i++) {
            bf16x8_t fp0 = fragT(Pl, i * 16 + lr, 0, ls);
            bf16x8_t fp1 = fragT(Pl, i * 16 + lr, 1, ls);
            acc[i] = mfma_bf16(fv[0], fp0, acc[i]);
            acc[i] = mfma_bf16(fv[1], fp1, acc[i]);
        }
    }
#pragma unroll
    for (int i = 0; i < 4; i++) {
        float v2 = psums[i];
        v2 += __shfl_xor(v2, 16);
        v2 += __shfl_xor(v2, 32);
        if (ls == 0) red[wv][i * 16 + lr] = v2;
    }
    __syncthreads();
    if (tid < 64) {
        float t = red[0][tid] + red[1][tid] + red[2][tid] + red[3][tid];
        inv[tid] = 1.0f / (t + 1e-8f);
    }
    __syncthreads();
#pragma unroll
    for (int i = 0; i < 4; i++) {
        int qn = q0 + i * 16 + lr;
        if (qn < N_) {
            float rn = inv[i * 16 + lr];
            unsigned int h0 = bf16rne(acc[i][0] * rn);
            unsigned int h1 = bf16rne(acc[i][1] * rn);
            unsigned int h2 = bf16rne(acc[i][2] * rn);
            unsigned int h3 = bf16rne(acc[i][3] * rn);
            *(uint2*)&ctxb[((size_t)(b * N_ + qn)) * C_ + h * D_ + wv * 16 + ls * 4] =
                make_uint2(h0 | (h1 << 16), h2 | (h3 << 16));
        }
    }
}

// ---------------------------------------------------------------------------
// MFMA GEMM 2 (plain bf16): out = context_bf16 @ Wproj^T + bproj
// ---------------------------------------------------------------------------
__global__ __launch_bounds__(256) void gemm_proj_mfma(const ushort* __restrict__ Actx,
                                                      const float* __restrict__ W,
                                                      const float* __restrict__ bias,
                                                      float* __restrict__ out) {
    __shared__ ushort Ab[128 * 32], Bb[128 * 32];
    const int tid = threadIdx.x;
    const int lane = tid & 63, wave = tid >> 6;
    const int wr = wave >> 1, wc = wave & 1;
    const int lr = lane & 15, ls = lane >> 4;
    const int m0 = blockIdx.y * 128, n0 = blockIdx.x * 128;
    const int srow = tid >> 1, shalf = tid & 1;
    const int arow = min(m0 + srow, M_TOT - 1);
    const ushort* aptr = Actx + (size_t)arow * C_ + shalf * 16;
    const float* bptr = W + (size_t)(n0 + srow) * C_ + shalf * 16;
    const int swz = (srow >> 1) & 3;
    const int sidx = srow * 32;
    const int p0 = (shalf * 2 + 0) ^ swz, p1 = (shalf * 2 + 1) ^ swz;
    f32x4_t acc[4][4] = {};
#pragma unroll 1
    for (int k0 = 0; k0 < C_; k0 += 32) {
        __syncthreads();
        {
            u32x4_t c0 = *(const u32x4_t*)(aptr + k0);
            u32x4_t c1 = *(const u32x4_t*)(aptr + k0 + 8);
            *(u32x4_t*)&Ab[sidx + p0 * 8] = c0;
            *(u32x4_t*)&Ab[sidx + p1 * 8] = c1;
        }
        {
            float4 f0 = *(const float4*)(bptr + k0);
            float4 f1 = *(const float4*)(bptr + k0 + 4);
            float4 f2 = *(const float4*)(bptr + k0 + 8);
            float4 f3 = *(const float4*)(bptr + k0 + 12);
            unsigned int h[16];
            h[0] = bf16rne(f0.x);  h[1] = bf16rne(f0.y);
            h[2] = bf16rne(f0.z);  h[3] = bf16rne(f0.w);
            h[4] = bf16rne(f1.x);  h[5] = bf16rne(f1.y);
            h[6] = bf16rne(f1.z);  h[7] = bf16rne(f1.w);
            h[8] = bf16rne(f2.x);  h[9] = bf16rne(f2.y);
            h[10] = bf16rne(f2.z); h[11] = bf16rne(f2.w);
            h[12] = bf16rne(f3.x); h[13] = bf16rne(f3.y);
            h[14] = bf16rne(f3.z); h[15] = bf16rne(f3.w);
            u32x4_t hc0 = {h[0] | (h[1] << 16), h[2] | (h[3] << 16),
                           h[4] | (h[5] << 16), h[6] | (h[7] << 16)};
            u32x4_t hc1 = {h[8] | (h[9] << 16), h[10] | (h[11] << 16),
                           h[12] | (h[13] << 16), h[14] | (h[15] << 16)};
            *(u32x4_t*)&Bb[sidx + p0 * 8] = hc0;
            *(u32x4_t*)&Bb[sidx + p1 * 8] = hc1;
        }
        __syncthreads();
        bf16x8_t fa[4], fb[4];
#pragma unroll
        for (int i = 0; i < 4; i++) {
            int rowA = wr * 64 + i * 16 + lr;
            int pa = ls ^ ((rowA >> 1) & 3);
            fa[i] = __builtin_bit_cast(bf16x8_t, *(const u32x4_t*)&Ab[rowA * 32 + pa * 8]);
            int rowB = wc * 64 + i * 16 + lr;
            int pb = ls ^ ((rowB >> 1) & 3);
            fb[i] = __builtin_bit_cast(bf16x8_t, *(const u32x4_t*)&Bb[rowB * 32 + pb * 8]);
        }
#pragma unroll
        for (int i = 0; i < 4; i++)
#pragma unroll
            for (int j = 0; j < 4; j++)
                acc[i][j] = mfma_bf16(fa[i], fb[j], acc[i][j]);
    }
#pragma unroll
    for (int j = 0; j < 4; j++) {
        int ng = n0 + wc * 64 + j * 16 + lr;
        float bb = bias[ng];
#pragma unroll
        for (int i = 0; i < 4; i++) {
            int mg0 = m0 + wr * 64 + i * 16 + ls * 4;
#pragma unroll
            for (int r = 0; r < 4; r++) {
                int m = mg0 + r;
                if (m < M_TOT) out[(size_t)m * C_ + ng] = acc[i][j][r] + bb;
            }
        }
    }
}

// ---------------------------------------------------------------------------
extern "C" void kernel_launch(void* const* d_in, const int* in_sizes, int n_in,
                              void* d_out, int out_size, void* d_ws, size_t ws_size,
                              hipStream_t stream) {
    const float* x     = (const float*)d_in[0];
    const float* ucb   = (const float*)d_in[1];
    const float* Wqkv  = (const float*)d_in[2];
    const float* Wproj = (const float*)d_in[3];
    const float* bproj = (const float*)d_in[4];
    const int*   counter = (const int*)d_in[5];

    const size_t SZ  = (size_t)B_ * H_ * N_ * D_;  // 7,090,176
    const size_t BHN = (size_t)B_ * H_ * N_;       // 110,784
    float* q        = (float*)d_ws;
    float* k        = q + SZ;
    float* w        = k + SZ;
    float* colsum   = w + BHN;
    float* kvmask   = colsum + BHN;
    ushort* vb16    = (ushort*)(kvmask + (size_t)B_ * N_);
    ushort* vt      = vb16 + SZ;
    ushort* ctxb    = vt + (size_t)B_ * H_ * 64 * VTS;
    size_t need = ((char*)(ctxb + SZ)) - (char*)d_ws;
    if (ws_size < need) {
        fprintf(stderr, "kernel_launch: ws too small, need %zu have %zu\n",
                need, ws_size);
        return;
    }

    float* out  = (float*)d_out;
    float* sd   = out + (size_t)B_ * N_ * C_;
    float* kept = sd + (size_t)H_ * N_;

    hipMemsetAsync(kvmask, 0, (size_t)B_ * N_ * sizeof(float), stream);

    gemm_qkv_mfma<<<dim3(18, 73), 256, 0, stream>>>(x, Wqkv, q, k, vb16);
    vtrans_kernel<<<dim3(10, B_ * H_), 256, 0, stream>>>(vb16, vt);
    attn_rowsum_mfma<<<dim3(10, B_ * H_), 256, 0, stream>>>(q, k, w);
    attn_colsum_mfma<<<dim3(10, B_ * H_), 256, 0, stream>>>(q, k, w, colsum);
    topk_kernel<<<B_, 512, 0, stream>>>(colsum, ucb, counter, kept, kvmask);
    score_delta_kernel<<<(H_ * N_ + 255) / 256, 256, 0, stream>>>(kvmask, sd);
    attn_ctx_mfma<<<dim3(10, B_ * H_), 256, 0, stream>>>(q, k, vt, w, kvmask, ctxb);
    gemm_proj_mfma<<<dim3(6, 73), 256, 0, stream>>>(ctxb, Wproj, bproj, out);
}

// Round 5
// 400.271 us; speedup vs baseline: 4.7236x; 1.0112x over previous
//
#include <hip/hip_runtime.h>
#include <cstdio>
#include <cstdint>

// Problem constants
#define B_    16
#define N_    577
#define C_    768
#define H_    12
#define D_    64
#define KKEEP 288            // max(1, int(576*0.5))
#define SCALE 0.125f         // 64^-0.5 (exact power of 2)
#define M_TOT (B_ * N_)      // 9232
#define VTS   640            // vt row stride (>= 10*64, 16B-aligned)

typedef __bf16 bf16x8_t __attribute__((ext_vector_type(8)));
typedef float  f32x4_t  __attribute__((ext_vector_type(4)));
typedef unsigned int u32x4_t __attribute__((ext_vector_type(4)));

__device__ __forceinline__ f32x4_t mfma_bf16(bf16x8_t a, bf16x8_t b, f32x4_t c) {
    return __builtin_amdgcn_mfma_f32_16x16x32_bf16(a, b, c, 0, 0, 0);
}

// RTZ split of f32 into two bf16 bit patterns (x ~= hi + lo, err ~2^-16 |x|)
__device__ __forceinline__ void splitf(float x, unsigned int &hi, unsigned int &lo) {
    unsigned int u = __float_as_uint(x);
    hi = u >> 16;
    float r = x - __uint_as_float(u & 0xffff0000u);
    lo = __float_as_uint(r) >> 16;
}
__device__ __forceinline__ unsigned int bf16rne(float x) {
    unsigned int u = __float_as_uint(x);
    return (u + 0x7fffu + ((u >> 16) & 1u)) >> 16;
}
// packed-split pair merges: p = hi|lo<<16 per element
__device__ __forceinline__ unsigned hp(unsigned a, unsigned b) { return (a & 0xffffu) | (b << 16); }
__device__ __forceinline__ unsigned lp(unsigned a, unsigned b) { return (a >> 16) | (b & 0xffff0000u); }

__device__ __forceinline__ void unpack16(const unsigned* p, u32x4_t &hc0, u32x4_t &hc1,
                                         u32x4_t &lc0, u32x4_t &lc1) {
    hc0 = (u32x4_t){hp(p[0], p[1]), hp(p[2], p[3]), hp(p[4], p[5]), hp(p[6], p[7])};
    hc1 = (u32x4_t){hp(p[8], p[9]), hp(p[10], p[11]), hp(p[12], p[13]), hp(p[14], p[15])};
    lc0 = (u32x4_t){lp(p[0], p[1]), lp(p[2], p[3]), lp(p[4], p[5]), lp(p[6], p[7])};
    lc1 = (u32x4_t){lp(p[8], p[9]), lp(p[10], p[11]), lp(p[12], p[13]), lp(p[14], p[15])};
}

// ---------------------------------------------------------------------------
// Prepass: pack f32 -> u32 (hi-bf16 | lo-bf16<<16), 4 elems/thread
// ---------------------------------------------------------------------------
__global__ __launch_bounds__(256) void pack_split_kernel(const float* __restrict__ src,
                                                         unsigned* __restrict__ dst, int n4) {
    int i = blockIdx.x * 256 + threadIdx.x;
    if (i >= n4) return;
    float4 f = ((const float4*)src)[i];
    unsigned h, l;
    uint4 o;
    splitf(f.x, h, l); o.x = h | (l << 16);
    splitf(f.y, h, l); o.y = h | (l << 16);
    splitf(f.z, h, l); o.z = h | (l << 16);
    splitf(f.w, h, l); o.w = h | (l << 16);
    ((uint4*)dst)[i] = o;
}

// Prepass: f32 -> bf16 RNE, 8 elems/thread
__global__ __launch_bounds__(256) void pack_rne_kernel(const float* __restrict__ src,
                                                       ushort* __restrict__ dst, int n8) {
    int i = blockIdx.x * 256 + threadIdx.x;
    if (i >= n8) return;
    float4 f0 = ((const float4*)src)[2 * i];
    float4 f1 = ((const float4*)src)[2 * i + 1];
    u32x4_t o = {bf16rne(f0.x) | (bf16rne(f0.y) << 16),
                 bf16rne(f0.z) | (bf16rne(f0.w) << 16),
                 bf16rne(f1.x) | (bf16rne(f1.y) << 16),
                 bf16rne(f1.z) | (bf16rne(f1.w) << 16)};
    *(u32x4_t*)&dst[(size_t)i * 8] = o;
}

// ===========================================================================
// 64x64 bf16 LDS tiles: 64 ushort/row, 8 slots of 8; phys slot = logical^(row&7)
// ===========================================================================
__device__ __forceinline__ bf16x8_t fragT(const ushort* H, int row, int c, int ls) {
    int phys = ((c << 2) + ls) ^ (row & 7);
    return __builtin_bit_cast(bf16x8_t, *(const u32x4_t*)&H[(row << 6) + (phys << 3)]);
}

// stage 64x64 packed-split tile (rows row0.. from [N][64] u32) into Hh/Hl LDS
__device__ __forceinline__ void stage_packed64(const unsigned* __restrict__ base, int row0,
                                               ushort* Hh, ushort* Hl, int tid) {
    int r = tid >> 2, qd = tid & 3;
    int rn = row0 + r;
    unsigned p[16];
    if (rn < N_) {
        const unsigned* src = base + (size_t)rn * D_ + qd * 16;
        *(u32x4_t*)&p[0]  = *(const u32x4_t*)(src);
        *(u32x4_t*)&p[4]  = *(const u32x4_t*)(src + 4);
        *(u32x4_t*)&p[8]  = *(const u32x4_t*)(src + 8);
        *(u32x4_t*)&p[12] = *(const u32x4_t*)(src + 12);
    } else {
#pragma unroll
        for (int i = 0; i < 16; i++) p[i] = 0;
    }
    u32x4_t hc0, hc1, lc0, lc1;
    unpack16(p, hc0, hc1, lc0, lc1);
    int s0 = (2 * qd) ^ (r & 7), s1 = (2 * qd + 1) ^ (r & 7);
    *(u32x4_t*)&Hh[(r << 6) + (s0 << 3)] = hc0;
    *(u32x4_t*)&Hh[(r << 6) + (s1 << 3)] = hc1;
    *(u32x4_t*)&Hl[(r << 6) + (s0 << 3)] = lc0;
    *(u32x4_t*)&Hl[(r << 6) + (s1 << 3)] = lc1;
}

// stage 64x64 bf16 tile from vt (rows = d, row stride VTS), cols j0..j0+63
__device__ __forceinline__ void stage_vt(const ushort* __restrict__ vtb, int j0,
                                         ushort* Vt, int tid) {
    int r = tid >> 2, qd = tid & 3;
    const ushort* src = vtb + (size_t)r * VTS + j0 + qd * 16;
    u32x4_t c0 = *(const u32x4_t*)(src);
    u32x4_t c1 = *(const u32x4_t*)(src + 8);
    int s0 = (2 * qd) ^ (r & 7), s1 = (2 * qd + 1) ^ (r & 7);
    *(u32x4_t*)&Vt[(r << 6) + (s0 << 3)] = c0;
    *(u32x4_t*)&Vt[(r << 6) + (s1 << 3)] = c1;
}

// ---------------------------------------------------------------------------
// MFMA GEMM 1 (split precision, packed inputs): qkv = x @ Wqkv^T
// outputs: qpk/kpk packed-split u32 [B,H,N,D] (q pre-scaled), v -> vt bf16^T
// ---------------------------------------------------------------------------
__global__ __launch_bounds__(256) void gemm_qkv_mfma(const unsigned* __restrict__ Xpk,
                                                     const unsigned* __restrict__ Wpk,
                                                     unsigned* __restrict__ qpk,
                                                     unsigned* __restrict__ kpk,
                                                     ushort* __restrict__ vt) {
    __shared__ ushort Ah[128 * 32], Al[128 * 32], Bh[128 * 32], Bl[128 * 32];
    const int tid = threadIdx.x;
    const int lane = tid & 63, wave = tid >> 6;
    const int wr = wave >> 1, wc = wave & 1;
    const int lr = lane & 15, ls = lane >> 4;
    const int m0 = blockIdx.y * 128, n0 = blockIdx.x * 128;
    const int srow = tid >> 1, shalf = tid & 1;
    const int arow = min(m0 + srow, M_TOT - 1);
    const unsigned* aptr = Xpk + (size_t)arow * C_ + shalf * 16;
    const unsigned* bptr = Wpk + (size_t)(n0 + srow) * C_ + shalf * 16;
    const int swz = (srow >> 1) & 3;
    const int sidx = srow * 32;
    const int p0 = (shalf * 2 + 0) ^ swz, p1 = (shalf * 2 + 1) ^ swz;
    f32x4_t acc[4][4] = {};
#pragma unroll 1
    for (int k0 = 0; k0 < C_; k0 += 32) {
        __syncthreads();
        {
            unsigned p[16];
            *(u32x4_t*)&p[0]  = *(const u32x4_t*)(aptr + k0);
            *(u32x4_t*)&p[4]  = *(const u32x4_t*)(aptr + k0 + 4);
            *(u32x4_t*)&p[8]  = *(const u32x4_t*)(aptr + k0 + 8);
            *(u32x4_t*)&p[12] = *(const u32x4_t*)(aptr + k0 + 12);
            u32x4_t hc0, hc1, lc0, lc1;
            unpack16(p, hc0, hc1, lc0, lc1);
            *(u32x4_t*)&Ah[sidx + p0 * 8] = hc0;
            *(u32x4_t*)&Ah[sidx + p1 * 8] = hc1;
            *(u32x4_t*)&Al[sidx + p0 * 8] = lc0;
            *(u32x4_t*)&Al[sidx + p1 * 8] = lc1;
        }
        {
            unsigned p[16];
            *(u32x4_t*)&p[0]  = *(const u32x4_t*)(bptr + k0);
            *(u32x4_t*)&p[4]  = *(const u32x4_t*)(bptr + k0 + 4);
            *(u32x4_t*)&p[8]  = *(const u32x4_t*)(bptr + k0 + 8);
            *(u32x4_t*)&p[12] = *(const u32x4_t*)(bptr + k0 + 12);
            u32x4_t hc0, hc1, lc0, lc1;
            unpack16(p, hc0, hc1, lc0, lc1);
            *(u32x4_t*)&Bh[sidx + p0 * 8] = hc0;
            *(u32x4_t*)&Bh[sidx + p1 * 8] = hc1;
            *(u32x4_t*)&Bl[sidx + p0 * 8] = lc0;
            *(u32x4_t*)&Bl[sidx + p1 * 8] = lc1;
        }
        __syncthreads();
        bf16x8_t fah[4], fal[4], fbh[4], fbl[4];
#pragma unroll
        for (int i = 0; i < 4; i++) {
            int rowA = wr * 64 + i * 16 + lr;
            int pa = ls ^ ((rowA >> 1) & 3);
            fah[i] = __builtin_bit_cast(bf16x8_t, *(const u32x4_t*)&Ah[rowA * 32 + pa * 8]);
            fal[i] = __builtin_bit_cast(bf16x8_t, *(const u32x4_t*)&Al[rowA * 32 + pa * 8]);
            int rowB = wc * 64 + i * 16 + lr;
            int pb = ls ^ ((rowB >> 1) & 3);
            fbh[i] = __builtin_bit_cast(bf16x8_t, *(const u32x4_t*)&Bh[rowB * 32 + pb * 8]);
            fbl[i] = __builtin_bit_cast(bf16x8_t, *(const u32x4_t*)&Bl[rowB * 32 + pb * 8]);
        }
#pragma unroll
        for (int i = 0; i < 4; i++)
#pragma unroll
            for (int j = 0; j < 4; j++) {
                acc[i][j] = mfma_bf16(fah[i], fbh[j], acc[i][j]);
                acc[i][j] = mfma_bf16(fah[i], fbl[j], acc[i][j]);
                acc[i][j] = mfma_bf16(fal[i], fbh[j], acc[i][j]);
            }
    }
    const int s = n0 / C_;  // 0=q, 1=k, 2=v (block-uniform)
#pragma unroll
    for (int j = 0; j < 4; j++) {
        int ng = n0 + wc * 64 + j * 16 + lr;
        int hh = (ng % C_) / D_;
        int d = ng % D_;
#pragma unroll
        for (int i = 0; i < 4; i++) {
            int mg0 = m0 + wr * 64 + i * 16 + ls * 4;
#pragma unroll
            for (int r = 0; r < 4; r++) {
                int m = mg0 + r;
                if (m < M_TOT) {
                    int b = m / N_, n = m % N_;
                    if (s == 2) {
                        vt[((size_t)(b * H_ + hh) * D_ + d) * VTS + n] =
                            (ushort)bf16rne(acc[i][j][r]);
                    } else {
                        float val = acc[i][j][r];
                        if (s == 0) val *= SCALE;
                        unsigned hi, lo;
                        splitf(val, hi, lo);
                        unsigned* dst = (s == 1) ? kpk : qpk;
                        dst[((size_t)(b * H_ + hh) * N_ + n) * D_ + d] = hi | (lo << 16);
                    }
                }
            }
        }
    }
}

// ---------------------------------------------------------------------------
// Pass R: w[bh][q] = 1 / sum_j exp(s)   (swapped S^T MFMA, split, q prescaled)
// ---------------------------------------------------------------------------
__global__ __launch_bounds__(256) void attn_rowsum_mfma(const unsigned* __restrict__ qpk,
                                                        const unsigned* __restrict__ kpk,
                                                        float* __restrict__ w) {
    __shared__ ushort Qh[4096], Ql[4096], Kh[4096], Kl[4096];
    __shared__ float red[4][64];
    int bh = blockIdx.y, q0 = blockIdx.x * 64;
    int tid = threadIdx.x, lane = tid & 63, wv = tid >> 6;
    int lr = lane & 15, ls = lane >> 4;
    const unsigned* qb = qpk + (size_t)bh * N_ * D_;
    const unsigned* kb = kpk + (size_t)bh * N_ * D_;
    stage_packed64(qb, q0, Qh, Ql, tid);
    __syncthreads();
    bf16x8_t fqh[4][2], fql[4][2];   // B operand: n = q = i*16+lr
#pragma unroll
    for (int i = 0; i < 4; i++)
#pragma unroll
        for (int c = 0; c < 2; c++) {
            fqh[i][c] = fragT(Qh, i * 16 + lr, c, ls);
            fql[i][c] = fragT(Ql, i * 16 + lr, c, ls);
        }
    float rs[4] = {0.f, 0.f, 0.f, 0.f};
    for (int j0 = 0; j0 < N_; j0 += 64) {
        __syncthreads();
        stage_packed64(kb, j0, Kh, Kl, tid);
        __syncthreads();
        bf16x8_t fkh[2], fkl[2];     // A operand: m = j = wv*16+lr
#pragma unroll
        for (int c = 0; c < 2; c++) {
            fkh[c] = fragT(Kh, wv * 16 + lr, c, ls);
            fkl[c] = fragT(Kl, wv * 16 + lr, c, ls);
        }
        int jbase = j0 + wv * 16 + ls * 4;
#pragma unroll
        for (int i = 0; i < 4; i++) {
            f32x4_t s = {0.f, 0.f, 0.f, 0.f};
#pragma unroll
            for (int c = 0; c < 2; c++) {
                s = mfma_bf16(fkh[c], fqh[i][c], s);
                s = mfma_bf16(fkh[c], fql[i][c], s);
                s = mfma_bf16(fkl[c], fqh[i][c], s);
            }
#pragma unroll
            for (int r = 0; r < 4; r++)
                rs[i] += (jbase + r < N_) ? __expf(s[r]) : 0.f;
        }
    }
#pragma unroll
    for (int i = 0; i < 4; i++) {
        float v2 = rs[i];
        v2 += __shfl_xor(v2, 16);
        v2 += __shfl_xor(v2, 32);
        if (ls == 0) red[wv][i * 16 + lr] = v2;
    }
    __syncthreads();
    if (tid < 64) {
        float s = red[0][tid] + red[1][tid] + red[2][tid] + red[3][tid];
        int qn = q0 + tid;
        if (qn < N_) w[(size_t)bh * N_ + qn] = 1.0f / s;
    }
}

// ---------------------------------------------------------------------------
// Pass CS: colsum[bh][j] = sum_q exp(s)*w[q]   (natural S MFMA, split)
// ---------------------------------------------------------------------------
__global__ __launch_bounds__(256) void attn_colsum_mfma(const unsigned* __restrict__ qpk,
                                                        const unsigned* __restrict__ kpk,
                                                        const float* __restrict__ w,
                                                        float* __restrict__ colsum) {
    __shared__ ushort Qh[4096], Ql[4096], Kh[4096], Kl[4096];
    __shared__ float red[4][64];
    __shared__ float wsld[64];
    int bh = blockIdx.y, j0 = blockIdx.x * 64;
    int tid = threadIdx.x, lane = tid & 63, wv = tid >> 6;
    int lr = lane & 15, ls = lane >> 4;
    const unsigned* qb = qpk + (size_t)bh * N_ * D_;
    const unsigned* kb = kpk + (size_t)bh * N_ * D_;
    stage_packed64(kb, j0, Kh, Kl, tid);
    __syncthreads();
    bf16x8_t fkh[4][2], fkl[4][2];   // B operand: n = j = i*16+lr
#pragma unroll
    for (int i = 0; i < 4; i++)
#pragma unroll
        for (int c = 0; c < 2; c++) {
            fkh[i][c] = fragT(Kh, i * 16 + lr, c, ls);
            fkl[i][c] = fragT(Kl, i * 16 + lr, c, ls);
        }
    float cs[4] = {0.f, 0.f, 0.f, 0.f};
    for (int qt = 0; qt < N_; qt += 64) {
        __syncthreads();
        stage_packed64(qb, qt, Qh, Ql, tid);
        if (tid < 64) {
            int qn = qt + tid;
            wsld[tid] = (qn < N_) ? w[(size_t)bh * N_ + qn] : 0.f;
        }
        __syncthreads();
        bf16x8_t fqh[2], fql[2];     // A operand: m = q = wv*16+lr
#pragma unroll
        for (int c = 0; c < 2; c++) {
            fqh[c] = fragT(Qh, wv * 16 + lr, c, ls);
            fql[c] = fragT(Ql, wv * 16 + lr, c, ls);
        }
        float wq[4];
#pragma unroll
        for (int r = 0; r < 4; r++) wq[r] = wsld[wv * 16 + ls * 4 + r];
#pragma unroll
        for (int i = 0; i < 4; i++) {
            f32x4_t s = {0.f, 0.f, 0.f, 0.f};
#pragma unroll
            for (int c = 0; c < 2; c++) {
                s = mfma_bf16(fqh[c], fkh[i][c], s);
                s = mfma_bf16(fql[c], fkh[i][c], s);
                s = mfma_bf16(fqh[c], fkl[i][c], s);
            }
#pragma unroll
            for (int r = 0; r < 4; r++) cs[i] += __expf(s[r]) * wq[r];
        }
    }
#pragma unroll
    for (int i = 0; i < 4; i++) {
        float v2 = cs[i];
        v2 += __shfl_xor(v2, 16);
        v2 += __shfl_xor(v2, 32);
        if (ls == 0) red[wv][i * 16 + lr] = v2;
    }
    __syncthreads();
    if (tid < 64) {
        float t = red[0][tid] + red[1][tid] + red[2][tid] + red[3][tid];
        int jn = j0 + tid;
        if (jn < N_) colsum[(size_t)bh * N_ + jn] = t;
    }
}

// ---------------------------------------------------------------------------
// Top-k per batch: UCB scores + full bitonic sort (desc, ties -> lower index)
// ---------------------------------------------------------------------------
__global__ __launch_bounds__(512) void topk_kernel(const float* __restrict__ colsum,
                                                   const float* __restrict__ ucb_count,
                                                   const int* __restrict__ counter,
                                                   float* __restrict__ kept_out,
                                                   float* __restrict__ kvmask) {
    __shared__ float sv[1024];
    __shared__ int si[1024];
    int b = blockIdx.x, tid = threadIdx.x;
    float lc = logf((float)counter[0] + 1.0f);
    for (int t = tid; t < 1024; t += 512) {
        if (t < N_ - 1) {
            int tok = t + 1;
            float accv = 0.f;
#pragma unroll
            for (int h = 0; h < H_; h++) {
                float csv = colsum[(size_t)(b * H_ + h) * N_ + tok];
                float patch = csv * (1.0f / (float)N_);
                float cnt = ucb_count[h * N_ + tok];
                float expl = sqrtf(lc / (cnt + 1e-6f));
                accv += patch + expl;
            }
            sv[t] = accv * (1.0f / (float)H_);
            si[t] = t;
        } else {
            sv[t] = -INFINITY;
            si[t] = 1 << 20;
        }
    }
    __syncthreads();
    for (int kk = 2; kk <= 1024; kk <<= 1) {
        for (int jj = kk >> 1; jj > 0; jj >>= 1) {
            for (int t = tid; t < 1024; t += 512) {
                int ixj = t ^ jj;
                if (ixj > t) {
                    float v1 = sv[t], v2 = sv[ixj];
                    int i1 = si[t], i2 = si[ixj];
                    bool before21 = (v2 > v1) || (v2 == v1 && i2 < i1);
                    bool dirDesc = ((t & kk) == 0);
                    if (before21 == dirDesc) {
                        sv[t] = v2; sv[ixj] = v1;
                        si[t] = i2; si[ixj] = i1;
                    }
                }
            }
            __syncthreads();
        }
    }
    for (int r = tid; r < KKEEP; r += 512) {
        int tok = si[r] + 1;
        kept_out[b * KKEEP + r] = (float)tok;
        kvmask[b * N_ + tok] = 1.0f;
    }
    if (tid == 0) kvmask[b * N_] = 1.0f;  // CLS always kept
}

// ---------------------------------------------------------------------------
// score_delta[h,n] = (1/B) * count_b(token n kept)   (n=0 -> 0)
// ---------------------------------------------------------------------------
__global__ void score_delta_kernel(const float* __restrict__ kvmask,
                                   float* __restrict__ sd) {
    int idx = blockIdx.x * 256 + threadIdx.x;
    if (idx >= H_ * N_) return;
    int n = idx % N_;
    float d = 0.f;
    if (n != 0) {
#pragma unroll
        for (int b = 0; b < B_; b++) d += kvmask[b * N_ + n];
    }
    sd[idx] = d * (1.0f / (float)B_);
}

// ---------------------------------------------------------------------------
// Pass CTX: masked renormalized context -> bf16 [b,n, h*64+d]
// ---------------------------------------------------------------------------
__global__ __launch_bounds__(256) void attn_ctx_mfma(const unsigned* __restrict__ qpk,
                                                     const unsigned* __restrict__ kpk,
                                                     const ushort* __restrict__ vt,
                                                     const float* __restrict__ w,
                                                     const float* __restrict__ kvmask,
                                                     ushort* __restrict__ ctxb) {
    __shared__ ushort Qh[4096], Ql[4096], Kh[4096], Kl[4096], Vt[4096], Pl[4096];
    __shared__ float wsld[64], mqs[64], mjs[64], red[4][64], inv[64];
    int bh = blockIdx.y, b = bh / H_, h = bh % H_;
    int q0 = blockIdx.x * 64;
    int tid = threadIdx.x, lane = tid & 63, wv = tid >> 6;
    int lr = lane & 15, ls = lane >> 4;
    const unsigned* qbase = qpk + (size_t)bh * N_ * D_;
    const unsigned* kbase = kpk + (size_t)bh * N_ * D_;
    const ushort* vtb = vt + (size_t)bh * 64 * VTS;
    stage_packed64(qbase, q0, Qh, Ql, tid);
    if (tid < 64) {
        int qn = q0 + tid;
        wsld[tid] = (qn < N_) ? w[(size_t)bh * N_ + qn] : 0.f;
        mqs[tid]  = (qn < N_) ? kvmask[b * N_ + qn] : 0.f;
    }
    __syncthreads();
    bf16x8_t fqh[4][2], fql[4][2];
#pragma unroll
    for (int i = 0; i < 4; i++)
#pragma unroll
        for (int c = 0; c < 2; c++) {
            fqh[i][c] = fragT(Qh, i * 16 + lr, c, ls);
            fql[i][c] = fragT(Ql, i * 16 + lr, c, ls);
        }
    float wq[4], mq[4];
#pragma unroll
    for (int i = 0; i < 4; i++) { wq[i] = wsld[i * 16 + lr]; mq[i] = mqs[i * 16 + lr]; }
    f32x4_t acc[4] = {};
    float psums[4] = {0.f, 0.f, 0.f, 0.f};
    for (int j0t = 0; j0t < N_; j0t += 64) {
        __syncthreads();
        stage_packed64(kbase, j0t, Kh, Kl, tid);
        stage_vt(vtb, j0t, Vt, tid);
        if (tid < 64) {
            int jn = j0t + tid;
            mjs[tid] = (jn < N_) ? kvmask[b * N_ + jn] : 0.f;
        }
        __syncthreads();
        bf16x8_t fkh[2], fkl[2];
#pragma unroll
        for (int c = 0; c < 2; c++) {
            fkh[c] = fragT(Kh, wv * 16 + lr, c, ls);
            fkl[c] = fragT(Kl, wv * 16 + lr, c, ls);
        }
        int jloc = wv * 16 + ls * 4;
#pragma unroll
        for (int i = 0; i < 4; i++) {
            f32x4_t s = {0.f, 0.f, 0.f, 0.f};
#pragma unroll
            for (int c = 0; c < 2; c++) {
                s = mfma_bf16(fkh[c], fqh[i][c], s);
                s = mfma_bf16(fkh[c], fql[i][c], s);
                s = mfma_bf16(fkl[c], fqh[i][c], s);
            }
            unsigned int pk[4];
            float wqi = wq[i], mqi = mq[i];
#pragma unroll
            for (int r = 0; r < 4; r++) {
                int j = j0t + jloc + r;
                float mj = mjs[jloc + r];
                float p = (j < N_) ? __expf(s[r]) * wqi : 0.f;
                p = (mqi > 0.5f || mj > 0.5f) ? p : 0.f;
                psums[i] += p;
                pk[r] = bf16rne(p);
            }
            int row = i * 16 + lr;
            int slot = ((wv << 1) + (ls >> 1)) ^ (row & 7);
            *(uint2*)&Pl[(row << 6) + (slot << 3) + ((ls & 1) << 2)] =
                make_uint2(pk[0] | (pk[1] << 16), pk[2] | (pk[3] << 16));
        }
        __syncthreads();
        bf16x8_t fv[2];
#pragma unroll
        for (int c = 0; c < 2; c++) fv[c] = fragT(Vt, wv * 16 + lr, c, ls);
#pragma unroll
        for (int i = 0; i < 4; i++) {
            bf16x8_t fp0 = fragT(Pl, i * 16 + lr, 0, ls);
            bf16x8_t fp1 = fragT(Pl, i * 16 + lr, 1, ls);
            acc[i] = mfma_bf16(fv[0], fp0, acc[i]);
            acc[i] = mfma_bf16(fv[1], fp1, acc[i]);
        }
    }
#pragma unroll
    for (int i = 0; i < 4; i++) {
        float v2 = psums[i];
        v2 += __shfl_xor(v2, 16);
        v2 += __shfl_xor(v2, 32);
        if (ls == 0) red[wv][i * 16 + lr] = v2;
    }
    __syncthreads();
    if (tid < 64) {
        float t = red[0][tid] + red[1][tid] + red[2][tid] + red[3][tid];
        inv[tid] = 1.0f / (t + 1e-8f);
    }
    __syncthreads();
#pragma unroll
    for (int i = 0; i < 4; i++) {
        int qn = q0 + i * 16 + lr;
        if (qn < N_) {
            float rn = inv[i * 16 + lr];
            unsigned int h0 = bf16rne(acc[i][0] * rn);
            unsigned int h1 = bf16rne(acc[i][1] * rn);
            unsigned int h2 = bf16rne(acc[i][2] * rn);
            unsigned int h3 = bf16rne(acc[i][3] * rn);
            *(uint2*)&ctxb[((size_t)(b * N_ + qn)) * C_ + h * D_ + wv * 16 + ls * 4] =
                make_uint2(h0 | (h1 << 16), h2 | (h3 << 16));
        }
    }
}

// ---------------------------------------------------------------------------
// MFMA GEMM 2 (plain bf16, prepacked W): out = context_bf16 @ Wproj^T + bproj
// ---------------------------------------------------------------------------
__global__ __launch_bounds__(256) void gemm_proj_mfma(const ushort* __restrict__ Actx,
                                                      const ushort* __restrict__ Wb,
                                                      const float* __restrict__ bias,
                                                      float* __restrict__ out) {
    __shared__ ushort Ab[128 * 32], Bb[128 * 32];
    const int tid = threadIdx.x;
    const int lane = tid & 63, wave = tid >> 6;
    const int wr = wave >> 1, wc = wave & 1;
    const int lr = lane & 15, ls = lane >> 4;
    const int m0 = blockIdx.y * 128, n0 = blockIdx.x * 128;
    const int srow = tid >> 1, shalf = tid & 1;
    const int arow = min(m0 + srow, M_TOT - 1);
    const ushort* aptr = Actx + (size_t)arow * C_ + shalf * 16;
    const ushort* bptr = Wb + (size_t)(n0 + srow) * C_ + shalf * 16;
    const int swz = (srow >> 1) & 3;
    const int sidx = srow * 32;
    const int p0 = (shalf * 2 + 0) ^ swz, p1 = (shalf * 2 + 1) ^ swz;
    f32x4_t acc[4][4] = {};
#pragma unroll 1
    for (int k0 = 0; k0 < C_; k0 += 32) {
        __syncthreads();
        {
            u32x4_t c0 = *(const u32x4_t*)(aptr + k0);
            u32x4_t c1 = *(const u32x4_t*)(aptr + k0 + 8);
            *(u32x4_t*)&Ab[sidx + p0 * 8] = c0;
            *(u32x4_t*)&Ab[sidx + p1 * 8] = c1;
        }
        {
            u32x4_t c0 = *(const u32x4_t*)(bptr + k0);
            u32x4_t c1 = *(const u32x4_t*)(bptr + k0 + 8);
            *(u32x4_t*)&Bb[sidx + p0 * 8] = c0;
            *(u32x4_t*)&Bb[sidx + p1 * 8] = c1;
        }
        __syncthreads();
        bf16x8_t fa[4], fb[4];
#pragma unroll
        for (int i = 0; i < 4; i++) {
            int rowA = wr * 64 + i * 16 + lr;
            int pa = ls ^ ((rowA >> 1) & 3);
            fa[i] = __builtin_bit_cast(bf16x8_t, *(const u32x4_t*)&Ab[rowA * 32 + pa * 8]);
            int rowB = wc * 64 + i * 16 + lr;
            int pb = ls ^ ((rowB >> 1) & 3);
            fb[i] = __builtin_bit_cast(bf16x8_t, *(const u32x4_t*)&Bb[rowB * 32 + pb * 8]);
        }
#pragma unroll
        for (int i = 0; i < 4; i++)
#pragma unroll
            for (int j = 0; j < 4; j++)
                acc[i][j] = mfma_bf16(fa[i], fb[j], acc[i][j]);
    }
#pragma unroll
    for (int j = 0; j < 4; j++) {
        int ng = n0 + wc * 64 + j * 16 + lr;
        float bb = bias[ng];
#pragma unroll
        for (int i = 0; i < 4; i++) {
            int mg0 = m0 + wr * 64 + i * 16 + ls * 4;
#pragma unroll
            for (int r = 0; r < 4; r++) {
                int m = mg0 + r;
                if (m < M_TOT) out[(size_t)m * C_ + ng] = acc[i][j][r] + bb;
            }
        }
    }
}

// ---------------------------------------------------------------------------
extern "C" void kernel_launch(void* const* d_in, const int* in_sizes, int n_in,
                              void* d_out, int out_size, void* d_ws, size_t ws_size,
                              hipStream_t stream) {
    const float* x     = (const float*)d_in[0];
    const float* ucb   = (const float*)d_in[1];
    const float* Wqkv  = (const float*)d_in[2];
    const float* Wproj = (const float*)d_in[3];
    const float* bproj = (const float*)d_in[4];
    const int*   counter = (const int*)d_in[5];

    const size_t SZ   = (size_t)B_ * H_ * N_ * D_;  // 7,090,176 (== M_TOT*C_)
    const size_t BHN  = (size_t)B_ * H_ * N_;       // 110,784
    const size_t WSZ  = (size_t)3 * C_ * C_;        // 1,769,472
    const size_t WPJ  = (size_t)C_ * C_;            // 589,824
    const size_t VTSZ = (size_t)B_ * H_ * D_ * VTS; // 7,864,320

    unsigned* qpk  = (unsigned*)d_ws;
    unsigned* kpk  = qpk + SZ;
    unsigned* Xpk  = kpk + SZ;                 // aliased by ctxb after gemm_qkv
    ushort*   ctxb = (ushort*)Xpk;             // SZ ushorts (fits inside Xpk)
    unsigned* Wpk  = Xpk + SZ;
    ushort*   Wpjb = (ushort*)(Wpk + WSZ);
    ushort*   vt   = Wpjb + WPJ;
    float*    w    = (float*)(vt + VTSZ);
    float*    colsum = w + BHN;
    float*    kvmask = colsum + BHN;
    size_t need = ((char*)(kvmask + (size_t)B_ * N_)) - (char*)d_ws;
    if (ws_size < need) {
        fprintf(stderr, "kernel_launch: ws too small, need %zu have %zu\n",
                need, ws_size);
        return;
    }

    float* out  = (float*)d_out;
    float* sd   = out + (size_t)B_ * N_ * C_;
    float* kept = sd + (size_t)H_ * N_;

    hipMemsetAsync(kvmask, 0, (size_t)B_ * N_ * sizeof(float), stream);
    hipMemsetAsync(vt, 0, VTSZ * sizeof(ushort), stream);

    pack_split_kernel<<<(int)(SZ / 4 / 256), 256, 0, stream>>>(x, Xpk, (int)(SZ / 4));
    pack_split_kernel<<<(int)(WSZ / 4 / 256), 256, 0, stream>>>(Wqkv, Wpk, (int)(WSZ / 4));
    pack_rne_kernel<<<(int)(WPJ / 8 / 256), 256, 0, stream>>>(Wproj, Wpjb, (int)(WPJ / 8));

    gemm_qkv_mfma<<<dim3(18, 73), 256, 0, stream>>>(Xpk, Wpk, qpk, kpk, vt);
    attn_rowsum_mfma<<<dim3(10, B_ * H_), 256, 0, stream>>>(qpk, kpk, w);
    attn_colsum_mfma<<<dim3(10, B_ * H_), 256, 0, stream>>>(qpk, kpk, w, colsum);
    topk_kernel<<<B_, 512, 0, stream>>>(colsum, ucb, counter, kept, kvmask);
    score_delta_kernel<<<(H_ * N_ + 255) / 256, 256, 0, stream>>>(kvmask, sd);
    attn_ctx_mfma<<<dim3(10, B_ * H_), 256, 0, stream>>>(qpk, kpk, vt, w, kvmask, ctxb);
    gemm_proj_mfma<<<dim3(6, 73), 256, 0, stream>>>(ctxb, Wpjb, bproj, out);
}